// Round 2
// baseline (5360.841 us; speedup 1.0000x reference)
//
#include <hip/hip_runtime.h>
#include <math.h>

// Problem constants
#define VV   50000
#define CC0  2000
#define CC1  10000
#define ED   512
#define HD   1024
#define BBATCH 32
#define TT   128
#define HH1  256
#define HH2  64
#define SS1  8000
#define SS2  40000
#define NR   4064        // B*(T-1) = 32*127
#define G3   3072        // 3*H

// Workspace layout (offsets in floats). Total ~72.3 MB.
#define OFF_XP   0ull                      // 4064*3072 = 12,484,608
#define OFF_YS   12484608ull               // 4064*1024 =  4,161,536
#define OFF_H0   16646144ull               // 32768
#define OFF_H1   16678912ull               // 32768
#define OFF_P1   16711680ull               // 4064*256 = 1,040,384
#define OFF_P2   17752064ull               // 4064*64  =   260,096
#define OFF_SUM  18012160ull               // hsum,hsel,t1sum,t1sel,t2sum,t2sel (6*4064)
#define OFF_LOSS (OFF_SUM + 6ull*4064ull)  // 64 floats: [0]=loss, [16..23]=arrive, [24]=rel
#define OFF_INT  (OFF_LOSS + 64ull)        // int region: targets,hselc,list1,list2,cnt1,cnt2

#define ZERO_N (6*4064 + 64)

// ---------------------------------------------------------------------------
// init: copy h0, zero the sum/loss/barrier region and counters
__global__ void init_k(const float* __restrict__ hidden, float* __restrict__ h0,
                       float* __restrict__ zreg, int* __restrict__ cnt1, int* __restrict__ cnt2)
{
    int i = blockIdx.x * 256 + threadIdx.x;
    if (i < BBATCH * HD) h0[i] = hidden[i];
    int zi = i - BBATCH * HD;
    if (zi >= 0 && zi < ZERO_N) zreg[zi] = 0.f;
    if (zi == ZERO_N) { *cnt1 = 0; *cnt2 = 0; }
}

// prep: targets, head sel-cols, cluster row lists
__global__ void prep_k(const int* __restrict__ x, int* __restrict__ targets,
                       int* __restrict__ hselc, int* __restrict__ list1,
                       int* __restrict__ list2, int* __restrict__ cnt1, int* __restrict__ cnt2)
{
    int n = blockIdx.x * 256 + threadIdx.x;
    if (n >= NR) return;
    int b = n / 127, t = n % 127;
    int tgt = x[b * TT + t + 1];
    targets[n] = tgt;
    hselc[n] = (tgt < CC0) ? tgt : ((tgt < CC1) ? CC0 : CC0 + 1);
    if (tgt >= CC0 && tgt < CC1) list1[atomicAdd(cnt1, 1)] = n;
    else if (tgt >= CC1)         list2[atomicAdd(cnt2, 1)] = n;
}

// ---------------------------------------------------------------------------
// GEMM: xp[r, c] = dot(emb[tok(r)], w_ih[c]) + b_ih[c]
// row r = t*32 + b ; token = x[b*128 + t]
__global__ void __launch_bounds__(256)
gemm_xp_k(const int* __restrict__ x, const float* __restrict__ emb,
          const float* __restrict__ w_ih, const float* __restrict__ b_ih,
          float* __restrict__ xp)
{
    __shared__ float smem[2 * 16 * 132];
    __shared__ int tok[128];
    float* As = smem;
    float* Ws = smem + 16 * 132;
    const int tid = threadIdx.x;
    const int rbase = blockIdx.x * 128;
    const int cbase = blockIdx.y * 128;
    const int rg = tid >> 4, cg = tid & 15;
    const int rl = tid >> 1;
    const int kk0 = (tid & 1) * 8;

    if (tid < 128) {
        int r = rbase + tid;
        tok[tid] = (r < NR) ? x[(r & 31) * TT + (r >> 5)] : -1;
    }
    __syncthreads();

    float acc[8][8];
#pragma unroll
    for (int i = 0; i < 8; i++)
#pragma unroll
        for (int j = 0; j < 8; j++) acc[i][j] = 0.f;

    for (int k0 = 0; k0 < ED; k0 += 16) {
        int tk = tok[rl];
        float4 a0 = make_float4(0,0,0,0), a1 = a0;
        if (tk >= 0) {
            const float* ap = emb + (size_t)tk * ED + k0 + kk0;
            a0 = *(const float4*)(ap);
            a1 = *(const float4*)(ap + 4);
        }
        As[(kk0+0)*132 + rl] = a0.x; As[(kk0+1)*132 + rl] = a0.y;
        As[(kk0+2)*132 + rl] = a0.z; As[(kk0+3)*132 + rl] = a0.w;
        As[(kk0+4)*132 + rl] = a1.x; As[(kk0+5)*132 + rl] = a1.y;
        As[(kk0+6)*132 + rl] = a1.z; As[(kk0+7)*132 + rl] = a1.w;

        const float* wp = w_ih + (size_t)(cbase + rl) * ED + k0 + kk0;
        float4 w0 = *(const float4*)(wp);
        float4 w1 = *(const float4*)(wp + 4);
        Ws[(kk0+0)*132 + rl] = w0.x; Ws[(kk0+1)*132 + rl] = w0.y;
        Ws[(kk0+2)*132 + rl] = w0.z; Ws[(kk0+3)*132 + rl] = w0.w;
        Ws[(kk0+4)*132 + rl] = w1.x; Ws[(kk0+5)*132 + rl] = w1.y;
        Ws[(kk0+6)*132 + rl] = w1.z; Ws[(kk0+7)*132 + rl] = w1.w;
        __syncthreads();
#pragma unroll
        for (int kk = 0; kk < 16; kk++) {
            float4 va0 = *(float4*)&As[kk*132 + rg*8];
            float4 va1 = *(float4*)&As[kk*132 + rg*8 + 4];
            float4 vw0 = *(float4*)&Ws[kk*132 + cg*8];
            float4 vw1 = *(float4*)&Ws[kk*132 + cg*8 + 4];
            float av[8] = {va0.x,va0.y,va0.z,va0.w,va1.x,va1.y,va1.z,va1.w};
            float wv[8] = {vw0.x,vw0.y,vw0.z,vw0.w,vw1.x,vw1.y,vw1.z,vw1.w};
#pragma unroll
            for (int i = 0; i < 8; i++)
#pragma unroll
                for (int j = 0; j < 8; j++) acc[i][j] += av[i] * wv[j];
        }
        __syncthreads();
    }
#pragma unroll
    for (int i = 0; i < 8; i++) {
        int r = rbase + rg*8 + i;
        if (r >= NR) continue;
#pragma unroll
        for (int j = 0; j < 8; j++) {
            int c = cbase + cg*8 + j;
            xp[(size_t)r * G3 + c] = acc[i][j] + b_ih[c];
        }
    }
}

// ---------------------------------------------------------------------------
// GEMM from ys rows (n-ordered): EPI 0 = store to outC (ldc), EPI 1 = exp-sum head
template<int EPI>
__global__ void __launch_bounds__(256)
gemm_ys_k(const float* __restrict__ ys, const float* __restrict__ W, int ncols,
          float* __restrict__ outC, int ldc,
          float* __restrict__ gsum, float* __restrict__ gsel, const int* __restrict__ selcol)
{
    __shared__ float smem[2 * 16 * 132];
    __shared__ const float* aptr[128];
    float* As = smem;
    float* Ws = smem + 16 * 132;
    const int tid = threadIdx.x;
    const int rbase = blockIdx.x * 128;
    const int cbase = blockIdx.y * 128;
    const int rg = tid >> 4, cg = tid & 15;
    const int rl = tid >> 1;
    const int kk0 = (tid & 1) * 8;

    if (tid < 128) {
        int n = rbase + tid;
        if (n < NR) {
            int t = n % 127, b = n / 127;
            aptr[tid] = ys + (size_t)(t * BBATCH + b) * HD;
        } else aptr[tid] = nullptr;
    }
    __syncthreads();

    float acc[8][8];
#pragma unroll
    for (int i = 0; i < 8; i++)
#pragma unroll
        for (int j = 0; j < 8; j++) acc[i][j] = 0.f;

    for (int k0 = 0; k0 < HD; k0 += 16) {
        const float* ap = aptr[rl];
        float4 a0 = make_float4(0,0,0,0), a1 = a0;
        if (ap) { a0 = *(const float4*)(ap + k0 + kk0); a1 = *(const float4*)(ap + k0 + kk0 + 4); }
        As[(kk0+0)*132 + rl] = a0.x; As[(kk0+1)*132 + rl] = a0.y;
        As[(kk0+2)*132 + rl] = a0.z; As[(kk0+3)*132 + rl] = a0.w;
        As[(kk0+4)*132 + rl] = a1.x; As[(kk0+5)*132 + rl] = a1.y;
        As[(kk0+6)*132 + rl] = a1.z; As[(kk0+7)*132 + rl] = a1.w;

        int c = cbase + rl;
        float4 w0 = make_float4(0,0,0,0), w1 = w0;
        if (c < ncols) {
            const float* wp = W + (size_t)c * HD + k0 + kk0;
            w0 = *(const float4*)(wp);
            w1 = *(const float4*)(wp + 4);
        }
        Ws[(kk0+0)*132 + rl] = w0.x; Ws[(kk0+1)*132 + rl] = w0.y;
        Ws[(kk0+2)*132 + rl] = w0.z; Ws[(kk0+3)*132 + rl] = w0.w;
        Ws[(kk0+4)*132 + rl] = w1.x; Ws[(kk0+5)*132 + rl] = w1.y;
        Ws[(kk0+6)*132 + rl] = w1.z; Ws[(kk0+7)*132 + rl] = w1.w;
        __syncthreads();
#pragma unroll
        for (int kk = 0; kk < 16; kk++) {
            float4 va0 = *(float4*)&As[kk*132 + rg*8];
            float4 va1 = *(float4*)&As[kk*132 + rg*8 + 4];
            float4 vw0 = *(float4*)&Ws[kk*132 + cg*8];
            float4 vw1 = *(float4*)&Ws[kk*132 + cg*8 + 4];
            float av[8] = {va0.x,va0.y,va0.z,va0.w,va1.x,va1.y,va1.z,va1.w};
            float wv[8] = {vw0.x,vw0.y,vw0.z,vw0.w,vw1.x,vw1.y,vw1.z,vw1.w};
#pragma unroll
            for (int i = 0; i < 8; i++)
#pragma unroll
                for (int j = 0; j < 8; j++) acc[i][j] += av[i] * wv[j];
        }
        __syncthreads();
    }

    if constexpr (EPI == 0) {
#pragma unroll
        for (int i = 0; i < 8; i++) {
            int r = rbase + rg*8 + i;
            if (r >= NR) continue;
#pragma unroll
            for (int j = 0; j < 8; j++) {
                int c = cbase + cg*8 + j;
                if (c < ncols) outC[(size_t)r * ldc + c] = acc[i][j];
            }
        }
    } else {
        __syncthreads();
        float* red = smem;  // 128*17 = 2176 <= 4224
#pragma unroll
        for (int i = 0; i < 8; i++) {
            int r = rbase + rg*8 + i;
            float s = 0.f;
            if (r < NR) {
                int sc = selcol[r];
#pragma unroll
                for (int j = 0; j < 8; j++) {
                    int c = cbase + cg*8 + j;
                    if (c < ncols) {
                        s += __expf(acc[i][j]);
                        if (c == sc) gsel[r] = acc[i][j];
                    }
                }
            }
            red[(rg*8 + i) * 17 + cg] = s;
        }
        __syncthreads();
        if (tid < 128) {
            int r = rbase + tid;
            if (r < NR) {
                float tot = 0.f;
#pragma unroll
                for (int q = 0; q < 16; q++) tot += red[tid * 17 + q];
                atomicAdd(&gsum[r], tot);
            }
        }
    }
}

// ---------------------------------------------------------------------------
// Tail cluster GEMM + exp-sum over compacted rows. A row = proj + n*K.
__global__ void __launch_bounds__(256)
gemm_tail_k(const float* __restrict__ Aproj, int K, const float* __restrict__ W, int ncols,
            const int* __restrict__ list, const int* __restrict__ cntp,
            const int* __restrict__ targets, int lo,
            float* __restrict__ gsum, float* __restrict__ gsel)
{
    const int cnt = *cntp;
    const int rbase = blockIdx.x * 128;
    if (rbase >= cnt) return;
    __shared__ float smem[2 * 16 * 132];
    __shared__ int rown[128];
    float* As = smem;
    float* Ws = smem + 16 * 132;
    const int tid = threadIdx.x;
    const int cbase = blockIdx.y * 128;
    const int rg = tid >> 4, cg = tid & 15;
    const int rl = tid >> 1;
    const int kk0 = (tid & 1) * 8;

    if (tid < 128) {
        int ir = rbase + tid;
        rown[tid] = (ir < cnt) ? list[ir] : -1;
    }
    __syncthreads();

    float acc[8][8];
#pragma unroll
    for (int i = 0; i < 8; i++)
#pragma unroll
        for (int j = 0; j < 8; j++) acc[i][j] = 0.f;

    for (int k0 = 0; k0 < K; k0 += 16) {
        int n = rown[rl];
        float4 a0 = make_float4(0,0,0,0), a1 = a0;
        if (n >= 0) {
            const float* ap = Aproj + (size_t)n * K + k0 + kk0;
            a0 = *(const float4*)(ap);
            a1 = *(const float4*)(ap + 4);
        }
        As[(kk0+0)*132 + rl] = a0.x; As[(kk0+1)*132 + rl] = a0.y;
        As[(kk0+2)*132 + rl] = a0.z; As[(kk0+3)*132 + rl] = a0.w;
        As[(kk0+4)*132 + rl] = a1.x; As[(kk0+5)*132 + rl] = a1.y;
        As[(kk0+6)*132 + rl] = a1.z; As[(kk0+7)*132 + rl] = a1.w;

        int c = cbase + rl;
        float4 w0 = make_float4(0,0,0,0), w1 = w0;
        if (c < ncols) {
            const float* wp = W + (size_t)c * K + k0 + kk0;
            w0 = *(const float4*)(wp);
            w1 = *(const float4*)(wp + 4);
        }
        Ws[(kk0+0)*132 + rl] = w0.x; Ws[(kk0+1)*132 + rl] = w0.y;
        Ws[(kk0+2)*132 + rl] = w0.z; Ws[(kk0+3)*132 + rl] = w0.w;
        Ws[(kk0+4)*132 + rl] = w1.x; Ws[(kk0+5)*132 + rl] = w1.y;
        Ws[(kk0+6)*132 + rl] = w1.z; Ws[(kk0+7)*132 + rl] = w1.w;
        __syncthreads();
#pragma unroll
        for (int kk = 0; kk < 16; kk++) {
            float4 va0 = *(float4*)&As[kk*132 + rg*8];
            float4 va1 = *(float4*)&As[kk*132 + rg*8 + 4];
            float4 vw0 = *(float4*)&Ws[kk*132 + cg*8];
            float4 vw1 = *(float4*)&Ws[kk*132 + cg*8 + 4];
            float av[8] = {va0.x,va0.y,va0.z,va0.w,va1.x,va1.y,va1.z,va1.w};
            float wv[8] = {vw0.x,vw0.y,vw0.z,vw0.w,vw1.x,vw1.y,vw1.z,vw1.w};
#pragma unroll
            for (int i = 0; i < 8; i++)
#pragma unroll
                for (int j = 0; j < 8; j++) acc[i][j] += av[i] * wv[j];
        }
        __syncthreads();
    }

    __syncthreads();
    float* red = smem;
#pragma unroll
    for (int i = 0; i < 8; i++) {
        int n = rown[rg*8 + i];
        float s = 0.f;
        if (n >= 0) {
            int sc = targets[n] - lo;
#pragma unroll
            for (int j = 0; j < 8; j++) {
                int c = cbase + cg*8 + j;
                if (c < ncols) {
                    s += __expf(acc[i][j]);
                    if (c == sc) gsel[n] = acc[i][j];
                }
            }
        }
        red[(rg*8 + i) * 17 + cg] = s;
    }
    __syncthreads();
    if (tid < 128) {
        int n = rown[tid];
        if (n >= 0) {
            float tot = 0.f;
#pragma unroll
            for (int q = 0; q < 16; q++) tot += red[tid * 17 + q];
            atomicAdd(&gsum[n], tot);
        }
    }
}

// ---------------------------------------------------------------------------
// Persistent GRU: 256 blocks x 256 threads, one block per 4 h-columns.
// Block caches its 12 w_hh rows in LDS once; loops all 127 steps with a
// device-scope two-level grid barrier per step. Double-buffered h in global.
__global__ void __launch_bounds__(256, 1)
gru_persist_k(const float* __restrict__ xp, float* __restrict__ h0buf,
              float* __restrict__ h1buf, const float* __restrict__ w_hh,
              const float* __restrict__ b_hh, const int* __restrict__ lengths,
              float* __restrict__ ys, int* __restrict__ arrive, int* __restrict__ rel)
{
    __shared__ float wlds[12 * 1024];        // 48 KB: rr = jj*3+g -> row g*1024+j0+jj
    __shared__ float red[12 * 32 * 4];       // 6 KB: [(rr*32+b)*4 + p]
    const int tid = threadIdx.x;
    const int bid = blockIdx.x;
    const int j0 = bid * 4;

    // one-time: load w slice into LDS
#pragma unroll
    for (int i = 0; i < 12; i++) {
        int c = i * 256 + tid;               // f4-chunk id
        int rr = c >> 8, k4 = c & 255;
        int jj = rr / 3, g = rr % 3;
        const float* src = w_hh + (size_t)(g * HD + j0 + jj) * HD + k4 * 4;
        *(float4*)&wlds[rr * 1024 + k4 * 4] = *(const float4*)src;
    }

    const int bg  = tid >> 6;        // 0..3 (8 batches each)
    const int rrg = (tid >> 5) & 1;  // 0..1 (6 rows each)
    const int s   = tid & 31;        // k-split
    const int p   = s >> 3;          // octet id

    // gate-thread statics
    float bhr = 0.f, bhz = 0.f, bhn = 0.f;
    int lenb = 0, gb = 0, gjj = 0;
    if (tid < 128) {
        gjj = tid & 3; gb = tid >> 2;
        bhr = b_hh[j0 + gjj];
        bhz = b_hh[HD + j0 + gjj];
        bhn = b_hh[2 * HD + j0 + gjj];
        lenb = lengths[gb];
    }
    __syncthreads();

    for (int t = 0; t < TT - 1; t++) {
        const float* hcur = (t & 1) ? h1buf : h0buf;
        float* hnext = (t & 1) ? h0buf : h1buf;

        // gate prefetch (independent of this step's GEMM)
        float xr = 0.f, xz = 0.f, xn = 0.f, hold = 0.f;
        if (tid < 128) {
            const float* xpt = xp + ((size_t)t * BBATCH + gb) * G3 + j0 + gjj;
            xr = xpt[0]; xz = xpt[HD]; xn = xpt[2 * HD];
            hold = hcur[gb * HD + j0 + gjj];
        }

        // partial dot products: 8 batches x 6 rows over k in {q*128 + s*4 ..+3}
        float acc[8][6];
#pragma unroll
        for (int i = 0; i < 8; i++)
#pragma unroll
            for (int j = 0; j < 6; j++) acc[i][j] = 0.f;

#pragma unroll
        for (int q = 0; q < 8; q++) {
            const int k = q * 128 + s * 4;
            float4 wv[6];
#pragma unroll
            for (int rr = 0; rr < 6; rr++)
                wv[rr] = *(const float4*)&wlds[(rrg * 6 + rr) * 1024 + k];
#pragma unroll
            for (int bq = 0; bq < 8; bq++) {
                float4 hv = *(const float4*)&hcur[(size_t)(bg * 8 + bq) * HD + k];
#pragma unroll
                for (int rr = 0; rr < 6; rr++)
                    acc[bq][rr] += hv.x * wv[rr].x + hv.y * wv[rr].y
                                 + hv.z * wv[rr].z + hv.w * wv[rr].w;
            }
        }

        // reduce s-octets in-wave (lanes differing in s by 1,2,4)
#pragma unroll
        for (int bq = 0; bq < 8; bq++)
#pragma unroll
            for (int rr = 0; rr < 6; rr++) {
                float v = acc[bq][rr];
                v += __shfl_xor(v, 1);
                v += __shfl_xor(v, 2);
                v += __shfl_xor(v, 4);
                acc[bq][rr] = v;
            }
        if ((s & 7) == 0) {
#pragma unroll
            for (int bq = 0; bq < 8; bq++)
#pragma unroll
                for (int rr = 0; rr < 6; rr++)
                    red[(((rrg * 6 + rr) * 32) + bg * 8 + bq) * 4 + p] = acc[bq][rr];
        }
        __syncthreads();

        // gates
        if (tid < 128) {
            float hpv[3];
#pragma unroll
            for (int g = 0; g < 3; g++) {
                int rr_g = gjj * 3 + g;
                float4 v = *(const float4*)&red[((rr_g * 32) + gb) * 4];
                hpv[g] = (v.x + v.y) + (v.z + v.w);
            }
            float r = 1.f / (1.f + __expf(-(xr + hpv[0] + bhr)));
            float z = 1.f / (1.f + __expf(-(xz + hpv[1] + bhz)));
            float nv = tanhf(xn + r * (hpv[2] + bhn));
            bool valid = t < (lenb - 1);
            float hnew = valid ? (1.f - z) * nv + z * hold : hold;
            hnext[gb * HD + j0 + gjj] = hnew;
            ys[((size_t)t * BBATCH + gb) * HD + j0 + gjj] = valid ? hnew : 0.f;
        }

        // grid barrier (two-level, device scope)
        __syncthreads();
        if (tid == 0) {
            __threadfence();
            __hip_atomic_fetch_add(&arrive[bid & 7], 1, __ATOMIC_RELEASE,
                                   __HIP_MEMORY_SCOPE_AGENT);
            if (bid == 0) {
                const int target = 32 * (t + 1);
                for (int c = 0; c < 8; c++) {
                    int guard = 0;
                    while (__hip_atomic_load(&arrive[c], __ATOMIC_RELAXED,
                                             __HIP_MEMORY_SCOPE_AGENT) < target
                           && guard < (1 << 30)) guard++;
                }
                __hip_atomic_store(rel, t + 1, __ATOMIC_RELEASE,
                                   __HIP_MEMORY_SCOPE_AGENT);
            }
            int guard = 0;
            while (__hip_atomic_load(rel, __ATOMIC_RELAXED,
                                     __HIP_MEMORY_SCOPE_AGENT) < t + 1
                   && guard < (1 << 30)) guard++;
            __threadfence();
        }
        __syncthreads();
    }
}

// ---------------------------------------------------------------------------
__global__ void finish_k(const float* __restrict__ hsum, const float* __restrict__ hsel,
                         const float* __restrict__ t1sum, const float* __restrict__ t1sel,
                         const float* __restrict__ t2sum, const float* __restrict__ t2sel,
                         const int* __restrict__ targets, float* __restrict__ losssum)
{
    __shared__ float red[256];
    int n = blockIdx.x * 256 + threadIdx.x;
    float lp = 0.f;
    if (n < NR) {
        lp = hsel[n] - logf(hsum[n]);
        int tgt = targets[n];
        if (tgt >= CC1)      lp += t2sel[n] - logf(t2sum[n]);
        else if (tgt >= CC0) lp += t1sel[n] - logf(t1sum[n]);
    }
    red[threadIdx.x] = lp;
    __syncthreads();
    for (int s = 128; s > 0; s >>= 1) {
        if (threadIdx.x < s) red[threadIdx.x] += red[threadIdx.x + s];
        __syncthreads();
    }
    if (threadIdx.x == 0) atomicAdd(losssum, red[0]);
}

__global__ void out_k(const float* __restrict__ losssum, const float* __restrict__ hT,
                      float* __restrict__ out)
{
    int i = blockIdx.x * 256 + threadIdx.x;
    if (i == 0) out[0] = -losssum[0] / (float)NR;
    if (i < BBATCH * HD) out[1 + i] = hT[i];
}

// ---------------------------------------------------------------------------
extern "C" void kernel_launch(void* const* d_in, const int* in_sizes, int n_in,
                              void* d_out, int out_size, void* d_ws, size_t ws_size,
                              hipStream_t stream)
{
    const int*   x       = (const int*)d_in[0];
    const int*   lengths = (const int*)d_in[1];
    const float* hidden  = (const float*)d_in[2];
    const float* emb     = (const float*)d_in[3];
    const float* w_ih    = (const float*)d_in[4];
    const float* w_hh    = (const float*)d_in[5];
    const float* b_ih    = (const float*)d_in[6];
    const float* b_hh    = (const float*)d_in[7];
    const float* head_w  = (const float*)d_in[8];
    const float* p1      = (const float*)d_in[9];
    const float* t1      = (const float*)d_in[10];
    const float* p2      = (const float*)d_in[11];
    const float* t2      = (const float*)d_in[12];

    float* ws = (float*)d_ws;
    float* xp    = ws + OFF_XP;
    float* ys    = ws + OFF_YS;
    float* h0b   = ws + OFF_H0;
    float* h1b   = ws + OFF_H1;
    float* proj1 = ws + OFF_P1;
    float* proj2 = ws + OFF_P2;
    float* hsum  = ws + OFF_SUM;
    float* hsel  = hsum + 4064;
    float* t1sum = hsel + 4064;
    float* t1sel = t1sum + 4064;
    float* t2sum = t1sel + 4064;
    float* t2sel = t2sum + 4064;
    float* losss = ws + OFF_LOSS;
    int* arrive  = (int*)(losss + 16);   // 8 ints, zeroed by init_k
    int* rel     = (int*)(losss + 24);   // 1 int, zeroed by init_k
    int* ib      = (int*)(ws + OFF_INT);
    int* targets = ib;
    int* hselc   = ib + 4064;
    int* list1   = ib + 2 * 4064;
    int* list2   = ib + 3 * 4064;
    int* cnt1    = ib + 4 * 4064;
    int* cnt2    = cnt1 + 1;

    float* out = (float*)d_out;

    init_k<<<224, 256, 0, stream>>>(hidden, h0b, hsum, cnt1, cnt2);
    prep_k<<<16, 256, 0, stream>>>(x, targets, hselc, list1, list2, cnt1, cnt2);

    // xp = embed(x) @ w_ih^T + b_ih   [4064 x 3072]
    gemm_xp_k<<<dim3(32, 24), 256, 0, stream>>>(x, emb, w_ih, b_ih, xp);

    // GRU recurrence: one persistent kernel, internal per-step grid barrier
    gru_persist_k<<<256, 256, 0, stream>>>(xp, h0b, h1b, w_hh, b_hh, lengths,
                                           ys, arrive, rel);
    float* hT = h1b;   // after 127 steps (odd count) -> h1b

    // projections (all rows; cheap)
    gemm_ys_k<0><<<dim3(32, 2), 256, 0, stream>>>(ys, p1, HH1, proj1, HH1,
                                                  nullptr, nullptr, nullptr);
    gemm_ys_k<0><<<dim3(32, 1), 256, 0, stream>>>(ys, p2, HH2, proj2, HH2,
                                                  nullptr, nullptr, nullptr);
    // head logits + exp-sum + selected logit
    gemm_ys_k<1><<<dim3(32, 16), 256, 0, stream>>>(ys, head_w, CC0 + 2, nullptr, 0,
                                                   hsum, hsel, hselc);
    // tails over compacted cluster rows
    gemm_tail_k<<<dim3(32, 63), 256, 0, stream>>>(proj1, HH1, t1, SS1, list1, cnt1,
                                                  targets, CC0, t1sum, t1sel);
    gemm_tail_k<<<dim3(32, 313), 256, 0, stream>>>(proj2, HH2, t2, SS2, list2, cnt2,
                                                   targets, CC1, t2sum, t2sel);

    finish_k<<<16, 256, 0, stream>>>(hsum, hsel, t1sum, t1sel, t2sum, t2sel,
                                     targets, losss);
    out_k<<<128, 256, 0, stream>>>(losss, hT, out);
}

// Round 3
// 4100.938 us; speedup vs baseline: 1.3072x; 1.3072x over previous
//
#include <hip/hip_runtime.h>
#include <math.h>

// Problem constants
#define VV   50000
#define CC0  2000
#define CC1  10000
#define ED   512
#define HD   1024
#define BBATCH 32
#define TT   128
#define HH1  256
#define HH2  64
#define SS1  8000
#define SS2  40000
#define NR   4064        // B*(T-1) = 32*127
#define G3   3072        // 3*H

// Workspace layout (offsets in floats). Total ~72.3 MB.
#define OFF_XP   0ull                      // 4064*3072 = 12,484,608
#define OFF_YS   12484608ull               // 4064*1024 =  4,161,536
#define OFF_H0   16646144ull               // 32768
#define OFF_H1   16678912ull               // 32768
#define OFF_P1   16711680ull               // 4064*256 = 1,040,384
#define OFF_P2   17752064ull               // 4064*64  =   260,096
#define OFF_SUM  18012160ull               // hsum,hsel,t1sum,t1sel,t2sum,t2sel (6*4064)
#define OFF_LOSS (OFF_SUM + 6ull*4064ull)  // 64 floats (only [0] used)
#define OFF_INT  (OFF_LOSS + 64ull)        // ints: targets,hselc,list1,list2,cnt1,cnt2,barrier

#define ZERO_N (6*4064 + 64)

// ---------------------------------------------------------------------------
// init: copy h0, zero the sum/loss region, counters, and barrier lines
__global__ void init_k(const float* __restrict__ hidden, float* __restrict__ h0,
                       float* __restrict__ zreg, int* __restrict__ cnt1,
                       int* __restrict__ cnt2, int* __restrict__ bar)
{
    int i = blockIdx.x * 256 + threadIdx.x;
    if (i < BBATCH * HD) h0[i] = hidden[i];
    int zi = i - BBATCH * HD;
    if (zi >= 0 && zi < ZERO_N) zreg[zi] = 0.f;
    if (zi == ZERO_N) { *cnt1 = 0; *cnt2 = 0; }
    int bi = zi - (ZERO_N + 1);
    if (bi >= 0 && bi < 2048) bar[bi] = 0;
}

// prep: targets, head sel-cols, cluster row lists
__global__ void prep_k(const int* __restrict__ x, int* __restrict__ targets,
                       int* __restrict__ hselc, int* __restrict__ list1,
                       int* __restrict__ list2, int* __restrict__ cnt1, int* __restrict__ cnt2)
{
    int n = blockIdx.x * 256 + threadIdx.x;
    if (n >= NR) return;
    int b = n / 127, t = n % 127;
    int tgt = x[b * TT + t + 1];
    targets[n] = tgt;
    hselc[n] = (tgt < CC0) ? tgt : ((tgt < CC1) ? CC0 : CC0 + 1);
    if (tgt >= CC0 && tgt < CC1) list1[atomicAdd(cnt1, 1)] = n;
    else if (tgt >= CC1)         list2[atomicAdd(cnt2, 1)] = n;
}

// ---------------------------------------------------------------------------
// GEMM: xp[r, c] = dot(emb[tok(r)], w_ih[c]) + b_ih[c]
// row r = t*32 + b ; token = x[b*128 + t]
__global__ void __launch_bounds__(256)
gemm_xp_k(const int* __restrict__ x, const float* __restrict__ emb,
          const float* __restrict__ w_ih, const float* __restrict__ b_ih,
          float* __restrict__ xp)
{
    __shared__ float smem[2 * 16 * 132];
    __shared__ int tok[128];
    float* As = smem;
    float* Ws = smem + 16 * 132;
    const int tid = threadIdx.x;
    const int rbase = blockIdx.x * 128;
    const int cbase = blockIdx.y * 128;
    const int rg = tid >> 4, cg = tid & 15;
    const int rl = tid >> 1;
    const int kk0 = (tid & 1) * 8;

    if (tid < 128) {
        int r = rbase + tid;
        tok[tid] = (r < NR) ? x[(r & 31) * TT + (r >> 5)] : -1;
    }
    __syncthreads();

    float acc[8][8];
#pragma unroll
    for (int i = 0; i < 8; i++)
#pragma unroll
        for (int j = 0; j < 8; j++) acc[i][j] = 0.f;

    for (int k0 = 0; k0 < ED; k0 += 16) {
        int tk = tok[rl];
        float4 a0 = make_float4(0,0,0,0), a1 = a0;
        if (tk >= 0) {
            const float* ap = emb + (size_t)tk * ED + k0 + kk0;
            a0 = *(const float4*)(ap);
            a1 = *(const float4*)(ap + 4);
        }
        As[(kk0+0)*132 + rl] = a0.x; As[(kk0+1)*132 + rl] = a0.y;
        As[(kk0+2)*132 + rl] = a0.z; As[(kk0+3)*132 + rl] = a0.w;
        As[(kk0+4)*132 + rl] = a1.x; As[(kk0+5)*132 + rl] = a1.y;
        As[(kk0+6)*132 + rl] = a1.z; As[(kk0+7)*132 + rl] = a1.w;

        const float* wp = w_ih + (size_t)(cbase + rl) * ED + k0 + kk0;
        float4 w0 = *(const float4*)(wp);
        float4 w1 = *(const float4*)(wp + 4);
        Ws[(kk0+0)*132 + rl] = w0.x; Ws[(kk0+1)*132 + rl] = w0.y;
        Ws[(kk0+2)*132 + rl] = w0.z; Ws[(kk0+3)*132 + rl] = w0.w;
        Ws[(kk0+4)*132 + rl] = w1.x; Ws[(kk0+5)*132 + rl] = w1.y;
        Ws[(kk0+6)*132 + rl] = w1.z; Ws[(kk0+7)*132 + rl] = w1.w;
        __syncthreads();
#pragma unroll
        for (int kk = 0; kk < 16; kk++) {
            float4 va0 = *(float4*)&As[kk*132 + rg*8];
            float4 va1 = *(float4*)&As[kk*132 + rg*8 + 4];
            float4 vw0 = *(float4*)&Ws[kk*132 + cg*8];
            float4 vw1 = *(float4*)&Ws[kk*132 + cg*8 + 4];
            float av[8] = {va0.x,va0.y,va0.z,va0.w,va1.x,va1.y,va1.z,va1.w};
            float wv[8] = {vw0.x,vw0.y,vw0.z,vw0.w,vw1.x,vw1.y,vw1.z,vw1.w};
#pragma unroll
            for (int i = 0; i < 8; i++)
#pragma unroll
                for (int j = 0; j < 8; j++) acc[i][j] += av[i] * wv[j];
        }
        __syncthreads();
    }
#pragma unroll
    for (int i = 0; i < 8; i++) {
        int r = rbase + rg*8 + i;
        if (r >= NR) continue;
#pragma unroll
        for (int j = 0; j < 8; j++) {
            int c = cbase + cg*8 + j;
            xp[(size_t)r * G3 + c] = acc[i][j] + b_ih[c];
        }
    }
}

// ---------------------------------------------------------------------------
// GEMM from ys rows (n-ordered): EPI 0 = store to outC (ldc), EPI 1 = exp-sum head
template<int EPI>
__global__ void __launch_bounds__(256)
gemm_ys_k(const float* __restrict__ ys, const float* __restrict__ W, int ncols,
          float* __restrict__ outC, int ldc,
          float* __restrict__ gsum, float* __restrict__ gsel, const int* __restrict__ selcol)
{
    __shared__ float smem[2 * 16 * 132];
    __shared__ const float* aptr[128];
    float* As = smem;
    float* Ws = smem + 16 * 132;
    const int tid = threadIdx.x;
    const int rbase = blockIdx.x * 128;
    const int cbase = blockIdx.y * 128;
    const int rg = tid >> 4, cg = tid & 15;
    const int rl = tid >> 1;
    const int kk0 = (tid & 1) * 8;

    if (tid < 128) {
        int n = rbase + tid;
        if (n < NR) {
            int t = n % 127, b = n / 127;
            aptr[tid] = ys + (size_t)(t * BBATCH + b) * HD;
        } else aptr[tid] = nullptr;
    }
    __syncthreads();

    float acc[8][8];
#pragma unroll
    for (int i = 0; i < 8; i++)
#pragma unroll
        for (int j = 0; j < 8; j++) acc[i][j] = 0.f;

    for (int k0 = 0; k0 < HD; k0 += 16) {
        const float* ap = aptr[rl];
        float4 a0 = make_float4(0,0,0,0), a1 = a0;
        if (ap) { a0 = *(const float4*)(ap + k0 + kk0); a1 = *(const float4*)(ap + k0 + kk0 + 4); }
        As[(kk0+0)*132 + rl] = a0.x; As[(kk0+1)*132 + rl] = a0.y;
        As[(kk0+2)*132 + rl] = a0.z; As[(kk0+3)*132 + rl] = a0.w;
        As[(kk0+4)*132 + rl] = a1.x; As[(kk0+5)*132 + rl] = a1.y;
        As[(kk0+6)*132 + rl] = a1.z; As[(kk0+7)*132 + rl] = a1.w;

        int c = cbase + rl;
        float4 w0 = make_float4(0,0,0,0), w1 = w0;
        if (c < ncols) {
            const float* wp = W + (size_t)c * HD + k0 + kk0;
            w0 = *(const float4*)(wp);
            w1 = *(const float4*)(wp + 4);
        }
        Ws[(kk0+0)*132 + rl] = w0.x; Ws[(kk0+1)*132 + rl] = w0.y;
        Ws[(kk0+2)*132 + rl] = w0.z; Ws[(kk0+3)*132 + rl] = w0.w;
        Ws[(kk0+4)*132 + rl] = w1.x; Ws[(kk0+5)*132 + rl] = w1.y;
        Ws[(kk0+6)*132 + rl] = w1.z; Ws[(kk0+7)*132 + rl] = w1.w;
        __syncthreads();
#pragma unroll
        for (int kk = 0; kk < 16; kk++) {
            float4 va0 = *(float4*)&As[kk*132 + rg*8];
            float4 va1 = *(float4*)&As[kk*132 + rg*8 + 4];
            float4 vw0 = *(float4*)&Ws[kk*132 + cg*8];
            float4 vw1 = *(float4*)&Ws[kk*132 + cg*8 + 4];
            float av[8] = {va0.x,va0.y,va0.z,va0.w,va1.x,va1.y,va1.z,va1.w};
            float wv[8] = {vw0.x,vw0.y,vw0.z,vw0.w,vw1.x,vw1.y,vw1.z,vw1.w};
#pragma unroll
            for (int i = 0; i < 8; i++)
#pragma unroll
                for (int j = 0; j < 8; j++) acc[i][j] += av[i] * wv[j];
        }
        __syncthreads();
    }

    if constexpr (EPI == 0) {
#pragma unroll
        for (int i = 0; i < 8; i++) {
            int r = rbase + rg*8 + i;
            if (r >= NR) continue;
#pragma unroll
            for (int j = 0; j < 8; j++) {
                int c = cbase + cg*8 + j;
                if (c < ncols) outC[(size_t)r * ldc + c] = acc[i][j];
            }
        }
    } else {
        __syncthreads();
        float* red = smem;  // 128*17 = 2176 <= 4224
#pragma unroll
        for (int i = 0; i < 8; i++) {
            int r = rbase + rg*8 + i;
            float s = 0.f;
            if (r < NR) {
                int sc = selcol[r];
#pragma unroll
                for (int j = 0; j < 8; j++) {
                    int c = cbase + cg*8 + j;
                    if (c < ncols) {
                        s += __expf(acc[i][j]);
                        if (c == sc) gsel[r] = acc[i][j];
                    }
                }
            }
            red[(rg*8 + i) * 17 + cg] = s;
        }
        __syncthreads();
        if (tid < 128) {
            int r = rbase + tid;
            if (r < NR) {
                float tot = 0.f;
#pragma unroll
                for (int q = 0; q < 16; q++) tot += red[tid * 17 + q];
                atomicAdd(&gsum[r], tot);
            }
        }
    }
}

// ---------------------------------------------------------------------------
// Tail cluster GEMM + exp-sum over compacted rows. A row = proj + n*K.
__global__ void __launch_bounds__(256)
gemm_tail_k(const float* __restrict__ Aproj, int K, const float* __restrict__ W, int ncols,
            const int* __restrict__ list, const int* __restrict__ cntp,
            const int* __restrict__ targets, int lo,
            float* __restrict__ gsum, float* __restrict__ gsel)
{
    const int cnt = *cntp;
    const int rbase = blockIdx.x * 128;
    if (rbase >= cnt) return;
    __shared__ float smem[2 * 16 * 132];
    __shared__ int rown[128];
    float* As = smem;
    float* Ws = smem + 16 * 132;
    const int tid = threadIdx.x;
    const int cbase = blockIdx.y * 128;
    const int rg = tid >> 4, cg = tid & 15;
    const int rl = tid >> 1;
    const int kk0 = (tid & 1) * 8;

    if (tid < 128) {
        int ir = rbase + tid;
        rown[tid] = (ir < cnt) ? list[ir] : -1;
    }
    __syncthreads();

    float acc[8][8];
#pragma unroll
    for (int i = 0; i < 8; i++)
#pragma unroll
        for (int j = 0; j < 8; j++) acc[i][j] = 0.f;

    for (int k0 = 0; k0 < K; k0 += 16) {
        int n = rown[rl];
        float4 a0 = make_float4(0,0,0,0), a1 = a0;
        if (n >= 0) {
            const float* ap = Aproj + (size_t)n * K + k0 + kk0;
            a0 = *(const float4*)(ap);
            a1 = *(const float4*)(ap + 4);
        }
        As[(kk0+0)*132 + rl] = a0.x; As[(kk0+1)*132 + rl] = a0.y;
        As[(kk0+2)*132 + rl] = a0.z; As[(kk0+3)*132 + rl] = a0.w;
        As[(kk0+4)*132 + rl] = a1.x; As[(kk0+5)*132 + rl] = a1.y;
        As[(kk0+6)*132 + rl] = a1.z; As[(kk0+7)*132 + rl] = a1.w;

        int c = cbase + rl;
        float4 w0 = make_float4(0,0,0,0), w1 = w0;
        if (c < ncols) {
            const float* wp = W + (size_t)c * K + k0 + kk0;
            w0 = *(const float4*)(wp);
            w1 = *(const float4*)(wp + 4);
        }
        Ws[(kk0+0)*132 + rl] = w0.x; Ws[(kk0+1)*132 + rl] = w0.y;
        Ws[(kk0+2)*132 + rl] = w0.z; Ws[(kk0+3)*132 + rl] = w0.w;
        Ws[(kk0+4)*132 + rl] = w1.x; Ws[(kk0+5)*132 + rl] = w1.y;
        Ws[(kk0+6)*132 + rl] = w1.z; Ws[(kk0+7)*132 + rl] = w1.w;
        __syncthreads();
#pragma unroll
        for (int kk = 0; kk < 16; kk++) {
            float4 va0 = *(float4*)&As[kk*132 + rg*8];
            float4 va1 = *(float4*)&As[kk*132 + rg*8 + 4];
            float4 vw0 = *(float4*)&Ws[kk*132 + cg*8];
            float4 vw1 = *(float4*)&Ws[kk*132 + cg*8 + 4];
            float av[8] = {va0.x,va0.y,va0.z,va0.w,va1.x,va1.y,va1.z,va1.w};
            float wv[8] = {vw0.x,vw0.y,vw0.z,vw0.w,vw1.x,vw1.y,vw1.z,vw1.w};
#pragma unroll
            for (int i = 0; i < 8; i++)
#pragma unroll
                for (int j = 0; j < 8; j++) acc[i][j] += av[i] * wv[j];
        }
        __syncthreads();
    }

    __syncthreads();
    float* red = smem;
#pragma unroll
    for (int i = 0; i < 8; i++) {
        int n = rown[rg*8 + i];
        float s = 0.f;
        if (n >= 0) {
            int sc = targets[n] - lo;
#pragma unroll
            for (int j = 0; j < 8; j++) {
                int c = cbase + cg*8 + j;
                if (c < ncols) {
                    s += __expf(acc[i][j]);
                    if (c == sc) gsel[n] = acc[i][j];
                }
            }
        }
        red[(rg*8 + i) * 17 + cg] = s;
    }
    __syncthreads();
    if (tid < 128) {
        int n = rown[tid];
        if (n >= 0) {
            float tot = 0.f;
#pragma unroll
            for (int q = 0; q < 16; q++) tot += red[tid * 17 + q];
            atomicAdd(&gsum[n], tot);
        }
    }
}

// ---------------------------------------------------------------------------
// Persistent GRU: 256 blocks x 256 threads, one block per 4 h-columns.
// Block caches its 12 w_hh rows in LDS once; loops all 127 steps with a
// spread-counter two-level device-scope grid barrier. h double-buffered in
// global; h loads ping-pong prefetched to hide post-invalidate latency.
// Barrier layout: arr[c*32] (32 lines, 8 blocks each), relcp[c*32] (32 lines).
__global__ void __launch_bounds__(256, 1)
gru_persist_k(const float* __restrict__ xp, float* __restrict__ h0buf,
              float* __restrict__ h1buf, const float* __restrict__ w_hh,
              const float* __restrict__ b_hh, const int* __restrict__ lengths,
              float* __restrict__ ys, int* __restrict__ arr, int* __restrict__ relcp)
{
    __shared__ float wlds[12 * 1024];        // 48 KB: rr = jj*3+g -> row g*1024+j0+jj
    __shared__ float red[12 * 32 * 4];       // 6 KB: [(rr*32+b)*4 + p]
    const int tid = threadIdx.x;
    const int bid = blockIdx.x;
    const int j0 = bid * 4;

    // one-time: load w slice into LDS
#pragma unroll
    for (int i = 0; i < 12; i++) {
        int c = i * 256 + tid;               // f4-chunk id
        int rr = c >> 8, k4 = c & 255;
        int jj = rr / 3, g = rr % 3;
        const float* src = w_hh + (size_t)(g * HD + j0 + jj) * HD + k4 * 4;
        *(float4*)&wlds[rr * 1024 + k4 * 4] = *(const float4*)src;
    }

    const int bg  = tid >> 6;        // 0..3 (8 batches each)
    const int rrg = (tid >> 5) & 1;  // 0..1 (6 rows each)
    const int s   = tid & 31;        // k-split
    const int p   = s >> 3;          // octet id
    const int klane = s * 4;

    // gate-thread statics
    float bhr = 0.f, bhz = 0.f, bhn = 0.f;
    int lenb = 0, gb = 0, gjj = 0;
    if (tid < 128) {
        gjj = tid & 3; gb = tid >> 2;
        bhr = b_hh[j0 + gjj];
        bhz = b_hh[HD + j0 + gjj];
        bhn = b_hh[2 * HD + j0 + gjj];
        lenb = lengths[gb];
    }
    __syncthreads();

    for (int t = 0; t < TT - 1; t++) {
        const float* hcur = (t & 1) ? h1buf : h0buf;
        float* hnext = (t & 1) ? h0buf : h1buf;

        // gate prefetch (independent of this step's GEMM)
        float xr = 0.f, xz = 0.f, xn = 0.f, hold = 0.f;
        if (tid < 128) {
            const float* xpt = xp + ((size_t)t * BBATCH + gb) * G3 + j0 + gjj;
            xr = xpt[0]; xz = xpt[HD]; xn = xpt[2 * HD];
            hold = hcur[gb * HD + j0 + gjj];
        }

        // partial dot products: 8 batches x 6 rows over k in {q*128 + s*4 ..+3}
        float acc[8][6];
#pragma unroll
        for (int i = 0; i < 8; i++)
#pragma unroll
            for (int j = 0; j < 6; j++) acc[i][j] = 0.f;

        float4 hva[8], hvb[8];
#pragma unroll
        for (int bq = 0; bq < 8; bq++)
            hva[bq] = *(const float4*)&hcur[(size_t)(bg * 8 + bq) * HD + klane];

#pragma unroll
        for (int q = 0; q < 8; q++) {
            float4* cur = (q & 1) ? hvb : hva;
            float4* nxt = (q & 1) ? hva : hvb;
            if (q < 7) {
                const int kn = (q + 1) * 128 + klane;
#pragma unroll
                for (int bq = 0; bq < 8; bq++)
                    nxt[bq] = *(const float4*)&hcur[(size_t)(bg * 8 + bq) * HD + kn];
            }
            const int k = q * 128 + klane;
#pragma unroll
            for (int rr = 0; rr < 6; rr++) {
                float4 wv = *(const float4*)&wlds[(rrg * 6 + rr) * 1024 + k];
#pragma unroll
                for (int bq = 0; bq < 8; bq++)
                    acc[bq][rr] += cur[bq].x * wv.x + cur[bq].y * wv.y
                                 + cur[bq].z * wv.z + cur[bq].w * wv.w;
            }
        }

        // reduce s-octets in-wave (lanes differing in s by 1,2,4)
#pragma unroll
        for (int bq = 0; bq < 8; bq++)
#pragma unroll
            for (int rr = 0; rr < 6; rr++) {
                float v = acc[bq][rr];
                v += __shfl_xor(v, 1);
                v += __shfl_xor(v, 2);
                v += __shfl_xor(v, 4);
                acc[bq][rr] = v;
            }
        if ((s & 7) == 0) {
#pragma unroll
            for (int bq = 0; bq < 8; bq++)
#pragma unroll
                for (int rr = 0; rr < 6; rr++)
                    red[(((rrg * 6 + rr) * 32) + bg * 8 + bq) * 4 + p] = acc[bq][rr];
        }
        __syncthreads();

        // gates
        if (tid < 128) {
            float hpv[3];
#pragma unroll
            for (int g = 0; g < 3; g++) {
                int rr_g = gjj * 3 + g;
                float4 v = *(const float4*)&red[((rr_g * 32) + gb) * 4];
                hpv[g] = (v.x + v.y) + (v.z + v.w);
            }
            float r = 1.f / (1.f + __expf(-(xr + hpv[0] + bhr)));
            float z = 1.f / (1.f + __expf(-(xz + hpv[1] + bhz)));
            float nv = tanhf(xn + r * (hpv[2] + bhn));
            bool valid = t < (lenb - 1);
            float hnew = valid ? (1.f - z) * nv + z * hold : hold;
            hnext[gb * HD + j0 + gjj] = hnew;
            ys[((size_t)t * BBATCH + gb) * HD + j0 + gjj] = valid ? hnew : 0.f;
        }

        // ---- grid barrier: spread counters, central collect, fan-out release
        __syncthreads();
        if (tid == 0) {
            __threadfence();    // push h/ys writes to agent coherence point
            __hip_atomic_fetch_add(&arr[(bid & 31) * 32], 1, __ATOMIC_RELEASE,
                                   __HIP_MEMORY_SCOPE_AGENT);
        }
        if (bid == 0) {
            if (tid < 32) {
                const int target = 8 * (t + 1);     // 256 blocks / 32 counters
                int guard = 0;
                while (__hip_atomic_load(&arr[tid * 32], __ATOMIC_RELAXED,
                                         __HIP_MEMORY_SCOPE_AGENT) < target
                       && guard < (1 << 20)) {
                    __builtin_amdgcn_s_sleep(2);
                    guard++;
                }
                __hip_atomic_store(&relcp[tid * 32], t + 1, __ATOMIC_RELEASE,
                                   __HIP_MEMORY_SCOPE_AGENT);
            }
        } else if (tid == 0) {
            int guard = 0;
            while (__hip_atomic_load(&relcp[(bid & 31) * 32], __ATOMIC_RELAXED,
                                     __HIP_MEMORY_SCOPE_AGENT) < t + 1
                   && guard < (1 << 20)) {
                __builtin_amdgcn_s_sleep(2);
                guard++;
            }
        }
        if (tid == 0) __threadfence();  // acquire: invalidate caches before h reads
        __syncthreads();
    }
}

// ---------------------------------------------------------------------------
__global__ void finish_k(const float* __restrict__ hsum, const float* __restrict__ hsel,
                         const float* __restrict__ t1sum, const float* __restrict__ t1sel,
                         const float* __restrict__ t2sum, const float* __restrict__ t2sel,
                         const int* __restrict__ targets, float* __restrict__ losssum)
{
    __shared__ float red[256];
    int n = blockIdx.x * 256 + threadIdx.x;
    float lp = 0.f;
    if (n < NR) {
        lp = hsel[n] - logf(hsum[n]);
        int tgt = targets[n];
        if (tgt >= CC1)      lp += t2sel[n] - logf(t2sum[n]);
        else if (tgt >= CC0) lp += t1sel[n] - logf(t1sum[n]);
    }
    red[threadIdx.x] = lp;
    __syncthreads();
    for (int s = 128; s > 0; s >>= 1) {
        if (threadIdx.x < s) red[threadIdx.x] += red[threadIdx.x + s];
        __syncthreads();
    }
    if (threadIdx.x == 0) atomicAdd(losssum, red[0]);
}

__global__ void out_k(const float* __restrict__ losssum, const float* __restrict__ hT,
                      float* __restrict__ out)
{
    int i = blockIdx.x * 256 + threadIdx.x;
    if (i == 0) out[0] = -losssum[0] / (float)NR;
    if (i < BBATCH * HD) out[1 + i] = hT[i];
}

// ---------------------------------------------------------------------------
extern "C" void kernel_launch(void* const* d_in, const int* in_sizes, int n_in,
                              void* d_out, int out_size, void* d_ws, size_t ws_size,
                              hipStream_t stream)
{
    const int*   x       = (const int*)d_in[0];
    const int*   lengths = (const int*)d_in[1];
    const float* hidden  = (const float*)d_in[2];
    const float* emb     = (const float*)d_in[3];
    const float* w_ih    = (const float*)d_in[4];
    const float* w_hh    = (const float*)d_in[5];
    const float* b_ih    = (const float*)d_in[6];
    const float* b_hh    = (const float*)d_in[7];
    const float* head_w  = (const float*)d_in[8];
    const float* p1      = (const float*)d_in[9];
    const float* t1      = (const float*)d_in[10];
    const float* p2      = (const float*)d_in[11];
    const float* t2      = (const float*)d_in[12];

    float* ws = (float*)d_ws;
    float* xp    = ws + OFF_XP;
    float* ys    = ws + OFF_YS;
    float* h0b   = ws + OFF_H0;
    float* h1b   = ws + OFF_H1;
    float* proj1 = ws + OFF_P1;
    float* proj2 = ws + OFF_P2;
    float* hsum  = ws + OFF_SUM;
    float* hsel  = hsum + 4064;
    float* t1sum = hsel + 4064;
    float* t1sel = t1sum + 4064;
    float* t2sum = t1sel + 4064;
    float* t2sel = t2sum + 4064;
    float* losss = ws + OFF_LOSS;
    int* ib      = (int*)(ws + OFF_INT);
    int* targets = ib;
    int* hselc   = ib + 4064;
    int* list1   = ib + 2 * 4064;
    int* list2   = ib + 3 * 4064;
    int* cnt1    = ib + 4 * 4064;
    int* cnt2    = cnt1 + 1;
    int* bar     = ib + 5 * 4064;    // 2048 ints: arr (32 lines) + relcp (32 lines)
    int* arr     = bar;
    int* relcp   = bar + 1024;

    float* out = (float*)d_out;

    init_k<<<232, 256, 0, stream>>>(hidden, h0b, hsum, cnt1, cnt2, bar);
    prep_k<<<16, 256, 0, stream>>>(x, targets, hselc, list1, list2, cnt1, cnt2);

    // xp = embed(x) @ w_ih^T + b_ih   [4064 x 3072]
    gemm_xp_k<<<dim3(32, 24), 256, 0, stream>>>(x, emb, w_ih, b_ih, xp);

    // GRU recurrence: one persistent kernel, internal per-step grid barrier
    gru_persist_k<<<256, 256, 0, stream>>>(xp, h0b, h1b, w_hh, b_hh, lengths,
                                           ys, arr, relcp);
    float* hT = h1b;   // after 127 steps (odd count) -> h1b

    // projections (all rows; cheap)
    gemm_ys_k<0><<<dim3(32, 2), 256, 0, stream>>>(ys, p1, HH1, proj1, HH1,
                                                  nullptr, nullptr, nullptr);
    gemm_ys_k<0><<<dim3(32, 1), 256, 0, stream>>>(ys, p2, HH2, proj2, HH2,
                                                  nullptr, nullptr, nullptr);
    // head logits + exp-sum + selected logit
    gemm_ys_k<1><<<dim3(32, 16), 256, 0, stream>>>(ys, head_w, CC0 + 2, nullptr, 0,
                                                   hsum, hsel, hselc);
    // tails over compacted cluster rows
    gemm_tail_k<<<dim3(32, 63), 256, 0, stream>>>(proj1, HH1, t1, SS1, list1, cnt1,
                                                  targets, CC0, t1sum, t1sel);
    gemm_tail_k<<<dim3(32, 313), 256, 0, stream>>>(proj2, HH2, t2, SS2, list2, cnt2,
                                                   targets, CC1, t2sum, t2sel);

    finish_k<<<16, 256, 0, stream>>>(hsum, hsel, t1sum, t1sel, t2sum, t2sel,
                                     targets, losss);
    out_k<<<128, 256, 0, stream>>>(losss, hT, out);
}

// Round 4
// 3631.968 us; speedup vs baseline: 1.4760x; 1.1291x over previous
//
#include <hip/hip_runtime.h>
#include <math.h>

// Problem constants
#define VV   50000
#define CC0  2000
#define CC1  10000
#define ED   512
#define HD   1024
#define BBATCH 32
#define TT   128
#define HH1  256
#define HH2  64
#define SS1  8000
#define SS2  40000
#define NR   4064        // B*(T-1) = 32*127
#define G3   3072        // 3*H

// Workspace layout (offsets in floats). Total ~72.3 MB.
#define OFF_XP   0ull                      // 4064*3072 = 12,484,608
#define OFF_YS   12484608ull               // 4064*1024 =  4,161,536
#define OFF_H0   16646144ull               // 32768
#define OFF_H1   16678912ull               // 32768
#define OFF_P1   16711680ull               // 4064*256 = 1,040,384
#define OFF_P2   17752064ull               // 4064*64  =   260,096
#define OFF_SUM  18012160ull               // hsum,hsel,t1sum,t1sel,t2sum,t2sel (6*4064)
#define OFF_LOSS (OFF_SUM + 6ull*4064ull)  // 64 floats (only [0] used)
#define OFF_INT  (OFF_LOSS + 64ull)        // ints: targets,hselc,list1,list2,cnt1,cnt2,barrier

#define ZERO_N (6*4064 + 64)

// LLC-coherent (cross-XCD) scalar access helpers: relaxed agent-scope atomics
// compile to global_load/store with sc0 sc1 — serviced at the coherent LLC,
// no L2 fence/invalidate needed.
__device__ __forceinline__ float agent_ld(const float* p) {
    return __hip_atomic_load(p, __ATOMIC_RELAXED, __HIP_MEMORY_SCOPE_AGENT);
}
__device__ __forceinline__ void agent_st(float* p, float v) {
    __hip_atomic_store(p, v, __ATOMIC_RELAXED, __HIP_MEMORY_SCOPE_AGENT);
}
__device__ __forceinline__ float4 agent_ld4(const float* p) {
    float4 v;
    v.x = agent_ld(p + 0);
    v.y = agent_ld(p + 1);
    v.z = agent_ld(p + 2);
    v.w = agent_ld(p + 3);
    return v;
}

// ---------------------------------------------------------------------------
// init: copy h0, zero the sum/loss region, counters, and barrier lines
__global__ void init_k(const float* __restrict__ hidden, float* __restrict__ h0,
                       float* __restrict__ zreg, int* __restrict__ cnt1,
                       int* __restrict__ cnt2, int* __restrict__ bar)
{
    int i = blockIdx.x * 256 + threadIdx.x;
    if (i < BBATCH * HD) h0[i] = hidden[i];
    int zi = i - BBATCH * HD;
    if (zi >= 0 && zi < ZERO_N) zreg[zi] = 0.f;
    if (zi == ZERO_N) { *cnt1 = 0; *cnt2 = 0; }
    int bi = zi - (ZERO_N + 1);
    if (bi >= 0 && bi < 2048) bar[bi] = 0;
}

// prep: targets, head sel-cols, cluster row lists
__global__ void prep_k(const int* __restrict__ x, int* __restrict__ targets,
                       int* __restrict__ hselc, int* __restrict__ list1,
                       int* __restrict__ list2, int* __restrict__ cnt1, int* __restrict__ cnt2)
{
    int n = blockIdx.x * 256 + threadIdx.x;
    if (n >= NR) return;
    int b = n / 127, t = n % 127;
    int tgt = x[b * TT + t + 1];
    targets[n] = tgt;
    hselc[n] = (tgt < CC0) ? tgt : ((tgt < CC1) ? CC0 : CC0 + 1);
    if (tgt >= CC0 && tgt < CC1) list1[atomicAdd(cnt1, 1)] = n;
    else if (tgt >= CC1)         list2[atomicAdd(cnt2, 1)] = n;
}

// ---------------------------------------------------------------------------
// GEMM: xp[r, c] = dot(emb[tok(r)], w_ih[c]) + b_ih[c]
// row r = t*32 + b ; token = x[b*128 + t]
__global__ void __launch_bounds__(256)
gemm_xp_k(const int* __restrict__ x, const float* __restrict__ emb,
          const float* __restrict__ w_ih, const float* __restrict__ b_ih,
          float* __restrict__ xp)
{
    __shared__ float smem[2 * 16 * 132];
    __shared__ int tok[128];
    float* As = smem;
    float* Ws = smem + 16 * 132;
    const int tid = threadIdx.x;
    const int rbase = blockIdx.x * 128;
    const int cbase = blockIdx.y * 128;
    const int rg = tid >> 4, cg = tid & 15;
    const int rl = tid >> 1;
    const int kk0 = (tid & 1) * 8;

    if (tid < 128) {
        int r = rbase + tid;
        tok[tid] = (r < NR) ? x[(r & 31) * TT + (r >> 5)] : -1;
    }
    __syncthreads();

    float acc[8][8];
#pragma unroll
    for (int i = 0; i < 8; i++)
#pragma unroll
        for (int j = 0; j < 8; j++) acc[i][j] = 0.f;

    for (int k0 = 0; k0 < ED; k0 += 16) {
        int tk = tok[rl];
        float4 a0 = make_float4(0,0,0,0), a1 = a0;
        if (tk >= 0) {
            const float* ap = emb + (size_t)tk * ED + k0 + kk0;
            a0 = *(const float4*)(ap);
            a1 = *(const float4*)(ap + 4);
        }
        As[(kk0+0)*132 + rl] = a0.x; As[(kk0+1)*132 + rl] = a0.y;
        As[(kk0+2)*132 + rl] = a0.z; As[(kk0+3)*132 + rl] = a0.w;
        As[(kk0+4)*132 + rl] = a1.x; As[(kk0+5)*132 + rl] = a1.y;
        As[(kk0+6)*132 + rl] = a1.z; As[(kk0+7)*132 + rl] = a1.w;

        const float* wp = w_ih + (size_t)(cbase + rl) * ED + k0 + kk0;
        float4 w0 = *(const float4*)(wp);
        float4 w1 = *(const float4*)(wp + 4);
        Ws[(kk0+0)*132 + rl] = w0.x; Ws[(kk0+1)*132 + rl] = w0.y;
        Ws[(kk0+2)*132 + rl] = w0.z; Ws[(kk0+3)*132 + rl] = w0.w;
        Ws[(kk0+4)*132 + rl] = w1.x; Ws[(kk0+5)*132 + rl] = w1.y;
        Ws[(kk0+6)*132 + rl] = w1.z; Ws[(kk0+7)*132 + rl] = w1.w;
        __syncthreads();
#pragma unroll
        for (int kk = 0; kk < 16; kk++) {
            float4 va0 = *(float4*)&As[kk*132 + rg*8];
            float4 va1 = *(float4*)&As[kk*132 + rg*8 + 4];
            float4 vw0 = *(float4*)&Ws[kk*132 + cg*8];
            float4 vw1 = *(float4*)&Ws[kk*132 + cg*8 + 4];
            float av[8] = {va0.x,va0.y,va0.z,va0.w,va1.x,va1.y,va1.z,va1.w};
            float wv[8] = {vw0.x,vw0.y,vw0.z,vw0.w,vw1.x,vw1.y,vw1.z,vw1.w};
#pragma unroll
            for (int i = 0; i < 8; i++)
#pragma unroll
                for (int j = 0; j < 8; j++) acc[i][j] += av[i] * wv[j];
        }
        __syncthreads();
    }
#pragma unroll
    for (int i = 0; i < 8; i++) {
        int r = rbase + rg*8 + i;
        if (r >= NR) continue;
#pragma unroll
        for (int j = 0; j < 8; j++) {
            int c = cbase + cg*8 + j;
            xp[(size_t)r * G3 + c] = acc[i][j] + b_ih[c];
        }
    }
}

// ---------------------------------------------------------------------------
// GEMM from ys rows (n-ordered): EPI 0 = store to outC (ldc), EPI 1 = exp-sum head
template<int EPI>
__global__ void __launch_bounds__(256)
gemm_ys_k(const float* __restrict__ ys, const float* __restrict__ W, int ncols,
          float* __restrict__ outC, int ldc,
          float* __restrict__ gsum, float* __restrict__ gsel, const int* __restrict__ selcol)
{
    __shared__ float smem[2 * 16 * 132];
    __shared__ const float* aptr[128];
    float* As = smem;
    float* Ws = smem + 16 * 132;
    const int tid = threadIdx.x;
    const int rbase = blockIdx.x * 128;
    const int cbase = blockIdx.y * 128;
    const int rg = tid >> 4, cg = tid & 15;
    const int rl = tid >> 1;
    const int kk0 = (tid & 1) * 8;

    if (tid < 128) {
        int n = rbase + tid;
        if (n < NR) {
            int t = n % 127, b = n / 127;
            aptr[tid] = ys + (size_t)(t * BBATCH + b) * HD;
        } else aptr[tid] = nullptr;
    }
    __syncthreads();

    float acc[8][8];
#pragma unroll
    for (int i = 0; i < 8; i++)
#pragma unroll
        for (int j = 0; j < 8; j++) acc[i][j] = 0.f;

    for (int k0 = 0; k0 < HD; k0 += 16) {
        const float* ap = aptr[rl];
        float4 a0 = make_float4(0,0,0,0), a1 = a0;
        if (ap) { a0 = *(const float4*)(ap + k0 + kk0); a1 = *(const float4*)(ap + k0 + kk0 + 4); }
        As[(kk0+0)*132 + rl] = a0.x; As[(kk0+1)*132 + rl] = a0.y;
        As[(kk0+2)*132 + rl] = a0.z; As[(kk0+3)*132 + rl] = a0.w;
        As[(kk0+4)*132 + rl] = a1.x; As[(kk0+5)*132 + rl] = a1.y;
        As[(kk0+6)*132 + rl] = a1.z; As[(kk0+7)*132 + rl] = a1.w;

        int c = cbase + rl;
        float4 w0 = make_float4(0,0,0,0), w1 = w0;
        if (c < ncols) {
            const float* wp = W + (size_t)c * HD + k0 + kk0;
            w0 = *(const float4*)(wp);
            w1 = *(const float4*)(wp + 4);
        }
        Ws[(kk0+0)*132 + rl] = w0.x; Ws[(kk0+1)*132 + rl] = w0.y;
        Ws[(kk0+2)*132 + rl] = w0.z; Ws[(kk0+3)*132 + rl] = w0.w;
        Ws[(kk0+4)*132 + rl] = w1.x; Ws[(kk0+5)*132 + rl] = w1.y;
        Ws[(kk0+6)*132 + rl] = w1.z; Ws[(kk0+7)*132 + rl] = w1.w;
        __syncthreads();
#pragma unroll
        for (int kk = 0; kk < 16; kk++) {
            float4 va0 = *(float4*)&As[kk*132 + rg*8];
            float4 va1 = *(float4*)&As[kk*132 + rg*8 + 4];
            float4 vw0 = *(float4*)&Ws[kk*132 + cg*8];
            float4 vw1 = *(float4*)&Ws[kk*132 + cg*8 + 4];
            float av[8] = {va0.x,va0.y,va0.z,va0.w,va1.x,va1.y,va1.z,va1.w};
            float wv[8] = {vw0.x,vw0.y,vw0.z,vw0.w,vw1.x,vw1.y,vw1.z,vw1.w};
#pragma unroll
            for (int i = 0; i < 8; i++)
#pragma unroll
                for (int j = 0; j < 8; j++) acc[i][j] += av[i] * wv[j];
        }
        __syncthreads();
    }

    if constexpr (EPI == 0) {
#pragma unroll
        for (int i = 0; i < 8; i++) {
            int r = rbase + rg*8 + i;
            if (r >= NR) continue;
#pragma unroll
            for (int j = 0; j < 8; j++) {
                int c = cbase + cg*8 + j;
                if (c < ncols) outC[(size_t)r * ldc + c] = acc[i][j];
            }
        }
    } else {
        __syncthreads();
        float* red = smem;  // 128*17 = 2176 <= 4224
#pragma unroll
        for (int i = 0; i < 8; i++) {
            int r = rbase + rg*8 + i;
            float s = 0.f;
            if (r < NR) {
                int sc = selcol[r];
#pragma unroll
                for (int j = 0; j < 8; j++) {
                    int c = cbase + cg*8 + j;
                    if (c < ncols) {
                        s += __expf(acc[i][j]);
                        if (c == sc) gsel[r] = acc[i][j];
                    }
                }
            }
            red[(rg*8 + i) * 17 + cg] = s;
        }
        __syncthreads();
        if (tid < 128) {
            int r = rbase + tid;
            if (r < NR) {
                float tot = 0.f;
#pragma unroll
                for (int q = 0; q < 16; q++) tot += red[tid * 17 + q];
                atomicAdd(&gsum[r], tot);
            }
        }
    }
}

// ---------------------------------------------------------------------------
// Tail cluster GEMM + exp-sum over compacted rows. A row = proj + n*K.
__global__ void __launch_bounds__(256)
gemm_tail_k(const float* __restrict__ Aproj, int K, const float* __restrict__ W, int ncols,
            const int* __restrict__ list, const int* __restrict__ cntp,
            const int* __restrict__ targets, int lo,
            float* __restrict__ gsum, float* __restrict__ gsel)
{
    const int cnt = *cntp;
    const int rbase = blockIdx.x * 128;
    if (rbase >= cnt) return;
    __shared__ float smem[2 * 16 * 132];
    __shared__ int rown[128];
    float* As = smem;
    float* Ws = smem + 16 * 132;
    const int tid = threadIdx.x;
    const int cbase = blockIdx.y * 128;
    const int rg = tid >> 4, cg = tid & 15;
    const int rl = tid >> 1;
    const int kk0 = (tid & 1) * 8;

    if (tid < 128) {
        int ir = rbase + tid;
        rown[tid] = (ir < cnt) ? list[ir] : -1;
    }
    __syncthreads();

    float acc[8][8];
#pragma unroll
    for (int i = 0; i < 8; i++)
#pragma unroll
        for (int j = 0; j < 8; j++) acc[i][j] = 0.f;

    for (int k0 = 0; k0 < K; k0 += 16) {
        int n = rown[rl];
        float4 a0 = make_float4(0,0,0,0), a1 = a0;
        if (n >= 0) {
            const float* ap = Aproj + (size_t)n * K + k0 + kk0;
            a0 = *(const float4*)(ap);
            a1 = *(const float4*)(ap + 4);
        }
        As[(kk0+0)*132 + rl] = a0.x; As[(kk0+1)*132 + rl] = a0.y;
        As[(kk0+2)*132 + rl] = a0.z; As[(kk0+3)*132 + rl] = a0.w;
        As[(kk0+4)*132 + rl] = a1.x; As[(kk0+5)*132 + rl] = a1.y;
        As[(kk0+6)*132 + rl] = a1.z; As[(kk0+7)*132 + rl] = a1.w;

        int c = cbase + rl;
        float4 w0 = make_float4(0,0,0,0), w1 = w0;
        if (c < ncols) {
            const float* wp = W + (size_t)c * K + k0 + kk0;
            w0 = *(const float4*)(wp);
            w1 = *(const float4*)(wp + 4);
        }
        Ws[(kk0+0)*132 + rl] = w0.x; Ws[(kk0+1)*132 + rl] = w0.y;
        Ws[(kk0+2)*132 + rl] = w0.z; Ws[(kk0+3)*132 + rl] = w0.w;
        Ws[(kk0+4)*132 + rl] = w1.x; Ws[(kk0+5)*132 + rl] = w1.y;
        Ws[(kk0+6)*132 + rl] = w1.z; Ws[(kk0+7)*132 + rl] = w1.w;
        __syncthreads();
#pragma unroll
        for (int kk = 0; kk < 16; kk++) {
            float4 va0 = *(float4*)&As[kk*132 + rg*8];
            float4 va1 = *(float4*)&As[kk*132 + rg*8 + 4];
            float4 vw0 = *(float4*)&Ws[kk*132 + cg*8];
            float4 vw1 = *(float4*)&Ws[kk*132 + cg*8 + 4];
            float av[8] = {va0.x,va0.y,va0.z,va0.w,va1.x,va1.y,va1.z,va1.w};
            float wv[8] = {vw0.x,vw0.y,vw0.z,vw0.w,vw1.x,vw1.y,vw1.z,vw1.w};
#pragma unroll
            for (int i = 0; i < 8; i++)
#pragma unroll
                for (int j = 0; j < 8; j++) acc[i][j] += av[i] * wv[j];
        }
        __syncthreads();
    }

    __syncthreads();
    float* red = smem;
#pragma unroll
    for (int i = 0; i < 8; i++) {
        int n = rown[rg*8 + i];
        float s = 0.f;
        if (n >= 0) {
            int sc = targets[n] - lo;
#pragma unroll
            for (int j = 0; j < 8; j++) {
                int c = cbase + cg*8 + j;
                if (c < ncols) {
                    s += __expf(acc[i][j]);
                    if (c == sc) gsel[n] = acc[i][j];
                }
            }
        }
        red[(rg*8 + i) * 17 + cg] = s;
    }
    __syncthreads();
    if (tid < 128) {
        int n = rown[tid];
        if (n >= 0) {
            float tot = 0.f;
#pragma unroll
            for (int q = 0; q < 16; q++) tot += red[tid * 17 + q];
            atomicAdd(&gsum[n], tot);
        }
    }
}

// ---------------------------------------------------------------------------
// Persistent GRU: 256 blocks x 256 threads, one block per 4 h-columns.
// Weights LDS-resident. h exchanged via LLC-coherent (sc0 sc1) relaxed
// agent atomics -> NO cache fences / L2 invalidates anywhere. Grid barrier:
// spread arrive counters (32 lines), central collect by block 0, fan-out
// release (32 lines); relaxed atomics + s_waitcnt(0) + compiler fence only.
__global__ void __launch_bounds__(256, 1)
gru_persist_k(const float* __restrict__ xp, float* __restrict__ h0buf,
              float* __restrict__ h1buf, const float* __restrict__ w_hh,
              const float* __restrict__ b_hh, const int* __restrict__ lengths,
              float* __restrict__ ys, int* __restrict__ arr, int* __restrict__ relcp)
{
    __shared__ float wlds[12 * 1024];        // 48 KB: rr = jj*3+g -> row g*1024+j0+jj
    __shared__ float red[12 * 32 * 4];       // 6 KB: [(rr*32+b)*4 + p]
    const int tid = threadIdx.x;
    const int bid = blockIdx.x;
    const int j0 = bid * 4;

    // one-time: load w slice into LDS
#pragma unroll
    for (int i = 0; i < 12; i++) {
        int c = i * 256 + tid;               // f4-chunk id
        int rr = c >> 8, k4 = c & 255;
        int jj = rr / 3, g = rr % 3;
        const float* src = w_hh + (size_t)(g * HD + j0 + jj) * HD + k4 * 4;
        *(float4*)&wlds[rr * 1024 + k4 * 4] = *(const float4*)src;
    }

    const int bg  = tid >> 6;        // 0..3 (8 batches each)
    const int rrg = (tid >> 5) & 1;  // 0..1 (6 rows each)
    const int s   = tid & 31;        // k-split
    const int p   = s >> 3;          // octet id
    const int klane = s * 4;

    // gate-thread statics; hold kept in a register across steps (own column)
    float bhr = 0.f, bhz = 0.f, bhn = 0.f, holdreg = 0.f;
    int lenb = 0, gb = 0, gjj = 0;
    if (tid < 128) {
        gjj = tid & 3; gb = tid >> 2;
        bhr = b_hh[j0 + gjj];
        bhz = b_hh[HD + j0 + gjj];
        bhn = b_hh[2 * HD + j0 + gjj];
        lenb = lengths[gb];
        holdreg = h0buf[gb * HD + j0 + gjj];   // init state (visible from init_k)
    }
    __syncthreads();

    for (int t = 0; t < TT - 1; t++) {
        const float* hcur = (t & 1) ? h1buf : h0buf;
        float* hnext = (t & 1) ? h0buf : h1buf;

        // gate xp prefetch (plain loads, L2-cacheable — never invalidated now)
        float xr = 0.f, xz = 0.f, xn = 0.f;
        if (tid < 128) {
            const float* xpt = xp + ((size_t)t * BBATCH + gb) * G3 + j0 + gjj;
            xr = xpt[0]; xz = xpt[HD]; xn = xpt[2 * HD];
        }

        // partial dot products: 8 batches x 6 rows over k in {q*128 + s*4 ..+3}
        float acc[8][6];
#pragma unroll
        for (int i = 0; i < 8; i++)
#pragma unroll
            for (int j = 0; j < 6; j++) acc[i][j] = 0.f;

        float4 hva[8], hvb[8];
#pragma unroll
        for (int bq = 0; bq < 8; bq++)
            hva[bq] = agent_ld4(&hcur[(size_t)(bg * 8 + bq) * HD + klane]);

#pragma unroll
        for (int q = 0; q < 8; q++) {
            float4* cur = (q & 1) ? hvb : hva;
            float4* nxt = (q & 1) ? hva : hvb;
            if (q < 7) {
                const int kn = (q + 1) * 128 + klane;
#pragma unroll
                for (int bq = 0; bq < 8; bq++)
                    nxt[bq] = agent_ld4(&hcur[(size_t)(bg * 8 + bq) * HD + kn]);
            }
            const int k = q * 128 + klane;
#pragma unroll
            for (int rr = 0; rr < 6; rr++) {
                float4 wv = *(const float4*)&wlds[(rrg * 6 + rr) * 1024 + k];
#pragma unroll
                for (int bq = 0; bq < 8; bq++)
                    acc[bq][rr] += cur[bq].x * wv.x + cur[bq].y * wv.y
                                 + cur[bq].z * wv.z + cur[bq].w * wv.w;
            }
        }

        // reduce s-octets in-wave (lanes differing in s by 1,2,4)
#pragma unroll
        for (int bq = 0; bq < 8; bq++)
#pragma unroll
            for (int rr = 0; rr < 6; rr++) {
                float v = acc[bq][rr];
                v += __shfl_xor(v, 1);
                v += __shfl_xor(v, 2);
                v += __shfl_xor(v, 4);
                acc[bq][rr] = v;
            }
        if ((s & 7) == 0) {
#pragma unroll
            for (int bq = 0; bq < 8; bq++)
#pragma unroll
                for (int rr = 0; rr < 6; rr++)
                    red[(((rrg * 6 + rr) * 32) + bg * 8 + bq) * 4 + p] = acc[bq][rr];
        }
        __syncthreads();

        // gates
        if (tid < 128) {
            float hpv[3];
#pragma unroll
            for (int g = 0; g < 3; g++) {
                int rr_g = gjj * 3 + g;
                float4 v = *(const float4*)&red[((rr_g * 32) + gb) * 4];
                hpv[g] = (v.x + v.y) + (v.z + v.w);
            }
            float r = 1.f / (1.f + __expf(-(xr + hpv[0] + bhr)));
            float z = 1.f / (1.f + __expf(-(xz + hpv[1] + bhz)));
            float nv = tanhf(xn + r * (hpv[2] + bhn));
            bool valid = t < (lenb - 1);
            float hnew = valid ? (1.f - z) * nv + z * holdreg : holdreg;
            holdreg = hnew;
            agent_st(&hnext[gb * HD + j0 + gjj], hnew);      // LLC-coherent
            ys[((size_t)t * BBATCH + gb) * HD + j0 + gjj] = valid ? hnew : 0.f;
        }

        // ---- grid barrier: no cache maintenance, relaxed atomics only ----
        __syncthreads();   // compiler drains vmcnt before s_barrier -> h stores acked at LLC
        if (tid == 0) {
            __builtin_amdgcn_s_waitcnt(0);   // belt & braces: all our vmem acked
            __hip_atomic_fetch_add(&arr[(bid & 31) * 32], 1, __ATOMIC_RELAXED,
                                   __HIP_MEMORY_SCOPE_AGENT);
        }
        if (bid == 0) {
            if (tid < 32) {
                const int target = 8 * (t + 1);     // 256 blocks / 32 counters
                int guard = 0;
                while (__hip_atomic_load(&arr[tid * 32], __ATOMIC_RELAXED,
                                         __HIP_MEMORY_SCOPE_AGENT) < target
                       && guard < (1 << 20)) {
                    __builtin_amdgcn_s_sleep(2);
                    guard++;
                }
                __hip_atomic_store(&relcp[tid * 32], t + 1, __ATOMIC_RELAXED,
                                   __HIP_MEMORY_SCOPE_AGENT);
            }
        } else if (tid == 0) {
            int guard = 0;
            while (__hip_atomic_load(&relcp[(bid & 31) * 32], __ATOMIC_RELAXED,
                                     __HIP_MEMORY_SCOPE_AGENT) < t + 1
                   && guard < (1 << 20)) {
                __builtin_amdgcn_s_sleep(2);
                guard++;
            }
        }
        asm volatile("" ::: "memory");   // compiler fence: nothing hoists above the poll
        __syncthreads();
    }
}

// ---------------------------------------------------------------------------
__global__ void finish_k(const float* __restrict__ hsum, const float* __restrict__ hsel,
                         const float* __restrict__ t1sum, const float* __restrict__ t1sel,
                         const float* __restrict__ t2sum, const float* __restrict__ t2sel,
                         const int* __restrict__ targets, float* __restrict__ losssum)
{
    __shared__ float red[256];
    int n = blockIdx.x * 256 + threadIdx.x;
    float lp = 0.f;
    if (n < NR) {
        lp = hsel[n] - logf(hsum[n]);
        int tgt = targets[n];
        if (tgt >= CC1)      lp += t2sel[n] - logf(t2sum[n]);
        else if (tgt >= CC0) lp += t1sel[n] - logf(t1sum[n]);
    }
    red[threadIdx.x] = lp;
    __syncthreads();
    for (int s = 128; s > 0; s >>= 1) {
        if (threadIdx.x < s) red[threadIdx.x] += red[threadIdx.x + s];
        __syncthreads();
    }
    if (threadIdx.x == 0) atomicAdd(losssum, red[0]);
}

__global__ void out_k(const float* __restrict__ losssum, const float* __restrict__ hT,
                      float* __restrict__ out)
{
    int i = blockIdx.x * 256 + threadIdx.x;
    if (i == 0) out[0] = -losssum[0] / (float)NR;
    if (i < BBATCH * HD) out[1 + i] = hT[i];
}

// ---------------------------------------------------------------------------
extern "C" void kernel_launch(void* const* d_in, const int* in_sizes, int n_in,
                              void* d_out, int out_size, void* d_ws, size_t ws_size,
                              hipStream_t stream)
{
    const int*   x       = (const int*)d_in[0];
    const int*   lengths = (const int*)d_in[1];
    const float* hidden  = (const float*)d_in[2];
    const float* emb     = (const float*)d_in[3];
    const float* w_ih    = (const float*)d_in[4];
    const float* w_hh    = (const float*)d_in[5];
    const float* b_ih    = (const float*)d_in[6];
    const float* b_hh    = (const float*)d_in[7];
    const float* head_w  = (const float*)d_in[8];
    const float* p1      = (const float*)d_in[9];
    const float* t1      = (const float*)d_in[10];
    const float* p2      = (const float*)d_in[11];
    const float* t2      = (const float*)d_in[12];

    float* ws = (float*)d_ws;
    float* xp    = ws + OFF_XP;
    float* ys    = ws + OFF_YS;
    float* h0b   = ws + OFF_H0;
    float* h1b   = ws + OFF_H1;
    float* proj1 = ws + OFF_P1;
    float* proj2 = ws + OFF_P2;
    float* hsum  = ws + OFF_SUM;
    float* hsel  = hsum + 4064;
    float* t1sum = hsel + 4064;
    float* t1sel = t1sum + 4064;
    float* t2sum = t1sel + 4064;
    float* t2sel = t2sum + 4064;
    float* losss = ws + OFF_LOSS;
    int* ib      = (int*)(ws + OFF_INT);
    int* targets = ib;
    int* hselc   = ib + 4064;
    int* list1   = ib + 2 * 4064;
    int* list2   = ib + 3 * 4064;
    int* cnt1    = ib + 4 * 4064;
    int* cnt2    = cnt1 + 1;
    int* bar     = ib + 5 * 4064;    // 2048 ints: arr (32 lines) + relcp (32 lines)
    int* arr     = bar;
    int* relcp   = bar + 1024;

    float* out = (float*)d_out;

    init_k<<<232, 256, 0, stream>>>(hidden, h0b, hsum, cnt1, cnt2, bar);
    prep_k<<<16, 256, 0, stream>>>(x, targets, hselc, list1, list2, cnt1, cnt2);

    // xp = embed(x) @ w_ih^T + b_ih   [4064 x 3072]
    gemm_xp_k<<<dim3(32, 24), 256, 0, stream>>>(x, emb, w_ih, b_ih, xp);

    // GRU recurrence: one persistent kernel, internal per-step grid barrier
    gru_persist_k<<<256, 256, 0, stream>>>(xp, h0b, h1b, w_hh, b_hh, lengths,
                                           ys, arr, relcp);
    float* hT = h1b;   // after 127 steps (odd count) -> h1b

    // projections (all rows; cheap)
    gemm_ys_k<0><<<dim3(32, 2), 256, 0, stream>>>(ys, p1, HH1, proj1, HH1,
                                                  nullptr, nullptr, nullptr);
    gemm_ys_k<0><<<dim3(32, 1), 256, 0, stream>>>(ys, p2, HH2, proj2, HH2,
                                                  nullptr, nullptr, nullptr);
    // head logits + exp-sum + selected logit
    gemm_ys_k<1><<<dim3(32, 16), 256, 0, stream>>>(ys, head_w, CC0 + 2, nullptr, 0,
                                                   hsum, hsel, hselc);
    // tails over compacted cluster rows
    gemm_tail_k<<<dim3(32, 63), 256, 0, stream>>>(proj1, HH1, t1, SS1, list1, cnt1,
                                                  targets, CC0, t1sum, t1sel);
    gemm_tail_k<<<dim3(32, 313), 256, 0, stream>>>(proj2, HH2, t2, SS2, list2, cnt2,
                                                   targets, CC1, t2sum, t2sel);

    finish_k<<<16, 256, 0, stream>>>(hsum, hsel, t1sum, t1sel, t2sum, t2sel,
                                     targets, losss);
    out_k<<<128, 256, 0, stream>>>(losss, hT, out);
}

// Round 5
// 2188.233 us; speedup vs baseline: 2.4498x; 1.6598x over previous
//
#include <hip/hip_runtime.h>
#include <math.h>

// Problem constants
#define VV   50000
#define CC0  2000
#define CC1  10000
#define ED   512
#define HD   1024
#define BBATCH 32
#define TT   128
#define HH1  256
#define HH2  64
#define SS1  8000
#define SS2  40000
#define NR   4064        // B*(T-1) = 32*127
#define G3   3072        // 3*H

// Workspace layout (offsets in floats). Total ~72.3 MB.
#define OFF_XP   0ull                      // 4064*3072 = 12,484,608
#define OFF_YS   12484608ull               // 4064*1024 =  4,161,536
#define OFF_H0   16646144ull               // 32768 floats: hb0/hb1 (bf16 x 32768 each)
#define OFF_H1   16678912ull               // 32768 floats: hT fp32
#define OFF_P1   16711680ull               // 4064*256 = 1,040,384
#define OFF_P2   17752064ull               // 4064*64  =   260,096
#define OFF_SUM  18012160ull               // hsum,hsel,t1sum,t1sel,t2sum,t2sel (6*4064)
#define OFF_LOSS (OFF_SUM + 6ull*4064ull)  // 64 floats (only [0] used)
#define OFF_INT  (OFF_LOSS + 64ull)        // ints: targets,hselc,list1,list2,cnt1,cnt2,barrier

#define ZERO_N (6*4064 + 64)
#define NBG 64            // GRU grid

typedef __attribute__((ext_vector_type(8))) __bf16 bf16x8;
typedef __attribute__((ext_vector_type(4))) float f32x4;
typedef unsigned long long u64;
typedef unsigned short u16;
struct ull2s { u64 x, y; };

__device__ __forceinline__ u16 f2bf(float f) {
    unsigned u = __builtin_bit_cast(unsigned, f);
    u += 0x7fff + ((u >> 16) & 1);          // round-to-nearest-even
    return (u16)(u >> 16);
}

// ---------------------------------------------------------------------------
// init: h0 -> bf16 buffer, zero the sum/loss region, counters, barrier lines
__global__ void init_k(const float* __restrict__ hidden, u16* __restrict__ hb0,
                       float* __restrict__ zreg, int* __restrict__ cnt1,
                       int* __restrict__ cnt2, int* __restrict__ bar)
{
    int i = blockIdx.x * 256 + threadIdx.x;
    if (i < BBATCH * HD) hb0[i] = f2bf(hidden[i]);
    int zi = i - BBATCH * HD;
    if (zi >= 0 && zi < ZERO_N) zreg[zi] = 0.f;
    if (zi == ZERO_N) { *cnt1 = 0; *cnt2 = 0; }
    int bi = zi - (ZERO_N + 1);
    if (bi >= 0 && bi < 2048) bar[bi] = 0;
}

// prep: targets, head sel-cols, cluster row lists
__global__ void prep_k(const int* __restrict__ x, int* __restrict__ targets,
                       int* __restrict__ hselc, int* __restrict__ list1,
                       int* __restrict__ list2, int* __restrict__ cnt1, int* __restrict__ cnt2)
{
    int n = blockIdx.x * 256 + threadIdx.x;
    if (n >= NR) return;
    int b = n / 127, t = n % 127;
    int tgt = x[b * TT + t + 1];
    targets[n] = tgt;
    hselc[n] = (tgt < CC0) ? tgt : ((tgt < CC1) ? CC0 : CC0 + 1);
    if (tgt >= CC0 && tgt < CC1) list1[atomicAdd(cnt1, 1)] = n;
    else if (tgt >= CC1)         list2[atomicAdd(cnt2, 1)] = n;
}

// ---------------------------------------------------------------------------
// GEMM: xp[r, c] = dot(emb[tok(r)], w_ih[c]) + b_ih[c]
// row r = t*32 + b ; token = x[b*128 + t]
__global__ void __launch_bounds__(256)
gemm_xp_k(const int* __restrict__ x, const float* __restrict__ emb,
          const float* __restrict__ w_ih, const float* __restrict__ b_ih,
          float* __restrict__ xp)
{
    __shared__ float smem[2 * 16 * 132];
    __shared__ int tok[128];
    float* As = smem;
    float* Ws = smem + 16 * 132;
    const int tid = threadIdx.x;
    const int rbase = blockIdx.x * 128;
    const int cbase = blockIdx.y * 128;
    const int rg = tid >> 4, cg = tid & 15;
    const int rl = tid >> 1;
    const int kk0 = (tid & 1) * 8;

    if (tid < 128) {
        int r = rbase + tid;
        tok[tid] = (r < NR) ? x[(r & 31) * TT + (r >> 5)] : -1;
    }
    __syncthreads();

    float acc[8][8];
#pragma unroll
    for (int i = 0; i < 8; i++)
#pragma unroll
        for (int j = 0; j < 8; j++) acc[i][j] = 0.f;

    for (int k0 = 0; k0 < ED; k0 += 16) {
        int tk = tok[rl];
        float4 a0 = make_float4(0,0,0,0), a1 = a0;
        if (tk >= 0) {
            const float* ap = emb + (size_t)tk * ED + k0 + kk0;
            a0 = *(const float4*)(ap);
            a1 = *(const float4*)(ap + 4);
        }
        As[(kk0+0)*132 + rl] = a0.x; As[(kk0+1)*132 + rl] = a0.y;
        As[(kk0+2)*132 + rl] = a0.z; As[(kk0+3)*132 + rl] = a0.w;
        As[(kk0+4)*132 + rl] = a1.x; As[(kk0+5)*132 + rl] = a1.y;
        As[(kk0+6)*132 + rl] = a1.z; As[(kk0+7)*132 + rl] = a1.w;

        const float* wp = w_ih + (size_t)(cbase + rl) * ED + k0 + kk0;
        float4 w0 = *(const float4*)(wp);
        float4 w1 = *(const float4*)(wp + 4);
        Ws[(kk0+0)*132 + rl] = w0.x; Ws[(kk0+1)*132 + rl] = w0.y;
        Ws[(kk0+2)*132 + rl] = w0.z; Ws[(kk0+3)*132 + rl] = w0.w;
        Ws[(kk0+4)*132 + rl] = w1.x; Ws[(kk0+5)*132 + rl] = w1.y;
        Ws[(kk0+6)*132 + rl] = w1.z; Ws[(kk0+7)*132 + rl] = w1.w;
        __syncthreads();
#pragma unroll
        for (int kk = 0; kk < 16; kk++) {
            float4 va0 = *(float4*)&As[kk*132 + rg*8];
            float4 va1 = *(float4*)&As[kk*132 + rg*8 + 4];
            float4 vw0 = *(float4*)&Ws[kk*132 + cg*8];
            float4 vw1 = *(float4*)&Ws[kk*132 + cg*8 + 4];
            float av[8] = {va0.x,va0.y,va0.z,va0.w,va1.x,va1.y,va1.z,va1.w};
            float wv[8] = {vw0.x,vw0.y,vw0.z,vw0.w,vw1.x,vw1.y,vw1.z,vw1.w};
#pragma unroll
            for (int i = 0; i < 8; i++)
#pragma unroll
                for (int j = 0; j < 8; j++) acc[i][j] += av[i] * wv[j];
        }
        __syncthreads();
    }
#pragma unroll
    for (int i = 0; i < 8; i++) {
        int r = rbase + rg*8 + i;
        if (r >= NR) continue;
#pragma unroll
        for (int j = 0; j < 8; j++) {
            int c = cbase + cg*8 + j;
            xp[(size_t)r * G3 + c] = acc[i][j] + b_ih[c];
        }
    }
}

// ---------------------------------------------------------------------------
// GEMM from ys rows (n-ordered): EPI 0 = store to outC (ldc), EPI 1 = exp-sum head
template<int EPI>
__global__ void __launch_bounds__(256)
gemm_ys_k(const float* __restrict__ ys, const float* __restrict__ W, int ncols,
          float* __restrict__ outC, int ldc,
          float* __restrict__ gsum, float* __restrict__ gsel, const int* __restrict__ selcol)
{
    __shared__ float smem[2 * 16 * 132];
    __shared__ const float* aptr[128];
    float* As = smem;
    float* Ws = smem + 16 * 132;
    const int tid = threadIdx.x;
    const int rbase = blockIdx.x * 128;
    const int cbase = blockIdx.y * 128;
    const int rg = tid >> 4, cg = tid & 15;
    const int rl = tid >> 1;
    const int kk0 = (tid & 1) * 8;

    if (tid < 128) {
        int n = rbase + tid;
        if (n < NR) {
            int t = n % 127, b = n / 127;
            aptr[tid] = ys + (size_t)(t * BBATCH + b) * HD;
        } else aptr[tid] = nullptr;
    }
    __syncthreads();

    float acc[8][8];
#pragma unroll
    for (int i = 0; i < 8; i++)
#pragma unroll
        for (int j = 0; j < 8; j++) acc[i][j] = 0.f;

    for (int k0 = 0; k0 < HD; k0 += 16) {
        const float* ap = aptr[rl];
        float4 a0 = make_float4(0,0,0,0), a1 = a0;
        if (ap) { a0 = *(const float4*)(ap + k0 + kk0); a1 = *(const float4*)(ap + k0 + kk0 + 4); }
        As[(kk0+0)*132 + rl] = a0.x; As[(kk0+1)*132 + rl] = a0.y;
        As[(kk0+2)*132 + rl] = a0.z; As[(kk0+3)*132 + rl] = a0.w;
        As[(kk0+4)*132 + rl] = a1.x; As[(kk0+5)*132 + rl] = a1.y;
        As[(kk0+6)*132 + rl] = a1.z; As[(kk0+7)*132 + rl] = a1.w;

        int c = cbase + rl;
        float4 w0 = make_float4(0,0,0,0), w1 = w0;
        if (c < ncols) {
            const float* wp = W + (size_t)c * HD + k0 + kk0;
            w0 = *(const float4*)(wp);
            w1 = *(const float4*)(wp + 4);
        }
        Ws[(kk0+0)*132 + rl] = w0.x; Ws[(kk0+1)*132 + rl] = w0.y;
        Ws[(kk0+2)*132 + rl] = w0.z; Ws[(kk0+3)*132 + rl] = w0.w;
        Ws[(kk0+4)*132 + rl] = w1.x; Ws[(kk0+5)*132 + rl] = w1.y;
        Ws[(kk0+6)*132 + rl] = w1.z; Ws[(kk0+7)*132 + rl] = w1.w;
        __syncthreads();
#pragma unroll
        for (int kk = 0; kk < 16; kk++) {
            float4 va0 = *(float4*)&As[kk*132 + rg*8];
            float4 va1 = *(float4*)&As[kk*132 + rg*8 + 4];
            float4 vw0 = *(float4*)&Ws[kk*132 + cg*8];
            float4 vw1 = *(float4*)&Ws[kk*132 + cg*8 + 4];
            float av[8] = {va0.x,va0.y,va0.z,va0.w,va1.x,va1.y,va1.z,va1.w};
            float wv[8] = {vw0.x,vw0.y,vw0.z,vw0.w,vw1.x,vw1.y,vw1.z,vw1.w};
#pragma unroll
            for (int i = 0; i < 8; i++)
#pragma unroll
                for (int j = 0; j < 8; j++) acc[i][j] += av[i] * wv[j];
        }
        __syncthreads();
    }

    if constexpr (EPI == 0) {
#pragma unroll
        for (int i = 0; i < 8; i++) {
            int r = rbase + rg*8 + i;
            if (r >= NR) continue;
#pragma unroll
            for (int j = 0; j < 8; j++) {
                int c = cbase + cg*8 + j;
                if (c < ncols) outC[(size_t)r * ldc + c] = acc[i][j];
            }
        }
    } else {
        __syncthreads();
        float* red = smem;  // 128*17 = 2176 <= 4224
#pragma unroll
        for (int i = 0; i < 8; i++) {
            int r = rbase + rg*8 + i;
            float s = 0.f;
            if (r < NR) {
                int sc = selcol[r];
#pragma unroll
                for (int j = 0; j < 8; j++) {
                    int c = cbase + cg*8 + j;
                    if (c < ncols) {
                        s += __expf(acc[i][j]);
                        if (c == sc) gsel[r] = acc[i][j];
                    }
                }
            }
            red[(rg*8 + i) * 17 + cg] = s;
        }
        __syncthreads();
        if (tid < 128) {
            int r = rbase + tid;
            if (r < NR) {
                float tot = 0.f;
#pragma unroll
                for (int q = 0; q < 16; q++) tot += red[tid * 17 + q];
                atomicAdd(&gsum[r], tot);
            }
        }
    }
}

// ---------------------------------------------------------------------------
// Tail cluster GEMM + exp-sum over compacted rows. A row = proj + n*K.
__global__ void __launch_bounds__(256)
gemm_tail_k(const float* __restrict__ Aproj, int K, const float* __restrict__ W, int ncols,
            const int* __restrict__ list, const int* __restrict__ cntp,
            const int* __restrict__ targets, int lo,
            float* __restrict__ gsum, float* __restrict__ gsel)
{
    const int cnt = *cntp;
    const int rbase = blockIdx.x * 128;
    if (rbase >= cnt) return;
    __shared__ float smem[2 * 16 * 132];
    __shared__ int rown[128];
    float* As = smem;
    float* Ws = smem + 16 * 132;
    const int tid = threadIdx.x;
    const int cbase = blockIdx.y * 128;
    const int rg = tid >> 4, cg = tid & 15;
    const int rl = tid >> 1;
    const int kk0 = (tid & 1) * 8;

    if (tid < 128) {
        int ir = rbase + tid;
        rown[tid] = (ir < cnt) ? list[ir] : -1;
    }
    __syncthreads();

    float acc[8][8];
#pragma unroll
    for (int i = 0; i < 8; i++)
#pragma unroll
        for (int j = 0; j < 8; j++) acc[i][j] = 0.f;

    for (int k0 = 0; k0 < K; k0 += 16) {
        int n = rown[rl];
        float4 a0 = make_float4(0,0,0,0), a1 = a0;
        if (n >= 0) {
            const float* ap = Aproj + (size_t)n * K + k0 + kk0;
            a0 = *(const float4*)(ap);
            a1 = *(const float4*)(ap + 4);
        }
        As[(kk0+0)*132 + rl] = a0.x; As[(kk0+1)*132 + rl] = a0.y;
        As[(kk0+2)*132 + rl] = a0.z; As[(kk0+3)*132 + rl] = a0.w;
        As[(kk0+4)*132 + rl] = a1.x; As[(kk0+5)*132 + rl] = a1.y;
        As[(kk0+6)*132 + rl] = a1.z; As[(kk0+7)*132 + rl] = a1.w;

        int c = cbase + rl;
        float4 w0 = make_float4(0,0,0,0), w1 = w0;
        if (c < ncols) {
            const float* wp = W + (size_t)c * K + k0 + kk0;
            w0 = *(const float4*)(wp);
            w1 = *(const float4*)(wp + 4);
        }
        Ws[(kk0+0)*132 + rl] = w0.x; Ws[(kk0+1)*132 + rl] = w0.y;
        Ws[(kk0+2)*132 + rl] = w0.z; Ws[(kk0+3)*132 + rl] = w0.w;
        Ws[(kk0+4)*132 + rl] = w1.x; Ws[(kk0+5)*132 + rl] = w1.y;
        Ws[(kk0+6)*132 + rl] = w1.z; Ws[(kk0+7)*132 + rl] = w1.w;
        __syncthreads();
#pragma unroll
        for (int kk = 0; kk < 16; kk++) {
            float4 va0 = *(float4*)&As[kk*132 + rg*8];
            float4 va1 = *(float4*)&As[kk*132 + rg*8 + 4];
            float4 vw0 = *(float4*)&Ws[kk*132 + cg*8];
            float4 vw1 = *(float4*)&Ws[kk*132 + cg*8 + 4];
            float av[8] = {va0.x,va0.y,va0.z,va0.w,va1.x,va1.y,va1.z,va1.w};
            float wv[8] = {vw0.x,vw0.y,vw0.z,vw0.w,vw1.x,vw1.y,vw1.z,vw1.w};
#pragma unroll
            for (int i = 0; i < 8; i++)
#pragma unroll
                for (int j = 0; j < 8; j++) acc[i][j] += av[i] * wv[j];
        }
        __syncthreads();
    }

    __syncthreads();
    float* red = smem;
#pragma unroll
    for (int i = 0; i < 8; i++) {
        int n = rown[rg*8 + i];
        float s = 0.f;
        if (n >= 0) {
            int sc = targets[n] - lo;
#pragma unroll
            for (int j = 0; j < 8; j++) {
                int c = cbase + cg*8 + j;
                if (c < ncols) {
                    s += __expf(acc[i][j]);
                    if (c == sc) gsel[n] = acc[i][j];
                }
            }
        }
        red[(rg*8 + i) * 17 + cg] = s;
    }
    __syncthreads();
    if (tid < 128) {
        int n = rown[tid];
        if (n >= 0) {
            float tot = 0.f;
#pragma unroll
            for (int q = 0; q < 16; q++) tot += red[tid * 17 + q];
            atomicAdd(&gsum[n], tot);
        }
    }
}

// ---------------------------------------------------------------------------
// Persistent MFMA GRU: 64 blocks x 128 threads (2 waves). Block owns 16
// h-columns; w slice (48 rows x 1024) bf16 in LDS (+8 pad). h state bf16 in
// global, double-buffered, exchanged via LLC-coherent 8B relaxed agent
// atomics. Per step, wave w computes hp for batches w*16..w*16+15 and the
// block's 16 cols via 96 MFMAs (16x16x32 bf16), then in-lane fp32 gates.
// Grid barrier: 16 spread counters + 16 release lines, relaxed atomics only.
__global__ void __launch_bounds__(128, 1)
gru_persist_k(const float* __restrict__ xp, const float* __restrict__ hidden,
              u16* __restrict__ hb0, u16* __restrict__ hb1,
              const float* __restrict__ w_hh, const float* __restrict__ b_hh,
              const int* __restrict__ lengths, float* __restrict__ ys,
              float* __restrict__ hT, int* __restrict__ arr, int* __restrict__ relcp)
{
    __shared__ u16 Blds[48 * 1032];          // 97 KB, row = g*16+c, +8 pad
    const int tid = threadIdx.x;
    const int bid = blockIdx.x;
    const int j0 = bid * 16;
    const int lane = tid & 63, wid = tid >> 6;
    const int n16 = lane & 15, quad = lane >> 4;

    // one-time: w_hh rows {g*1024 + j0 + c} -> bf16 LDS
    for (int idx = tid; idx < 48 * 1024; idx += 128) {
        int r = idx >> 10, k = idx & 1023;
        int g = r >> 4, c = r & 15;
        Blds[r * 1032 + k] = f2bf(w_hh[(size_t)(g * HD + j0 + c) * HD + k]);
    }

    const int col = j0 + n16;
    float bh0 = b_hh[col], bh1 = b_hh[HD + col], bh2 = b_hh[2 * HD + col];
    float hold[4];
    int len[4];
#pragma unroll
    for (int r = 0; r < 4; r++) {
        int b = wid * 16 + quad * 4 + r;
        len[r] = lengths[b];
        hold[r] = hidden[b * HD + col];
    }
    __syncthreads();

    for (int t = 0; t < TT - 1; t++) {
        const u16* hb = (t & 1) ? hb1 : hb0;
        u16* hbn = (t & 1) ? hb0 : hb1;

        // xp gate inputs (plain cacheable loads, issue early)
        float xrv[4], xzv[4], xnv[4];
#pragma unroll
        for (int r = 0; r < 4; r++) {
            int b = wid * 16 + quad * 4 + r;
            const float* xpt = xp + ((size_t)t * BBATCH + b) * G3 + col;
            xrv[r] = xpt[0]; xzv[r] = xpt[HD]; xnv[r] = xpt[2 * HD];
        }

        // prefetch A fragments: A[m = wid*16 + n16][k = ks*32 + quad*8 + j]
        const u16* arow = hb + (size_t)(wid * 16 + n16) * HD + quad * 8;
        u64 apf[64];
#pragma unroll
        for (int ks = 0; ks < 32; ks++) {
            apf[2*ks]   = __hip_atomic_load((const u64*)(arow + ks*32),
                                            __ATOMIC_RELAXED, __HIP_MEMORY_SCOPE_AGENT);
            apf[2*ks+1] = __hip_atomic_load((const u64*)(arow + ks*32 + 4),
                                            __ATOMIC_RELAXED, __HIP_MEMORY_SCOPE_AGENT);
        }

        f32x4 acc0 = {0.f, 0.f, 0.f, 0.f}, acc1 = acc0, acc2 = acc0;
        const int boff = n16 * 1032 + quad * 8;
#pragma unroll
        for (int ks = 0; ks < 32; ks++) {
            ull2s av2; av2.x = apf[2*ks]; av2.y = apf[2*ks+1];
            bf16x8 av = __builtin_bit_cast(bf16x8, av2);
            bf16x8 b0 = *(const bf16x8*)&Blds[boff + ks*32];
            bf16x8 b1 = *(const bf16x8*)&Blds[16*1032 + boff + ks*32];
            bf16x8 b2 = *(const bf16x8*)&Blds[32*1032 + boff + ks*32];
            acc0 = __builtin_amdgcn_mfma_f32_16x16x32_bf16(av, b0, acc0, 0, 0, 0);
            acc1 = __builtin_amdgcn_mfma_f32_16x16x32_bf16(av, b1, acc1, 0, 0, 0);
            acc2 = __builtin_amdgcn_mfma_f32_16x16x32_bf16(av, b2, acc2, 0, 0, 0);
        }

        // gates: C row = quad*4 + reg -> batch = wid*16 + quad*4 + reg, col = j0+n16
#pragma unroll
        for (int r = 0; r < 4; r++) {
            int b = wid * 16 + quad * 4 + r;
            float hr = acc0[r] + bh0, hz = acc1[r] + bh1, hn = acc2[r] + bh2;
            float rg = 1.f / (1.f + __expf(-(xrv[r] + hr)));
            float zg = 1.f / (1.f + __expf(-(xzv[r] + hz)));
            float nv = tanhf(xnv[r] + rg * hn);
            bool valid = t < (len[r] - 1);
            float hnew = valid ? (1.f - zg) * nv + zg * hold[r] : hold[r];
            hold[r] = hnew;
            __hip_atomic_store(hbn + (size_t)b * HD + col, f2bf(hnew),
                               __ATOMIC_RELAXED, __HIP_MEMORY_SCOPE_AGENT);
            ys[((size_t)t * BBATCH + b) * HD + col] = valid ? hnew : 0.f;
            if (t == TT - 2) hT[b * HD + col] = hnew;
        }

        // ---- grid barrier: 64 blocks, 16 spread counters, relaxed only ----
        __syncthreads();   // drains each wave's vmem before s_barrier
        if (tid == 0) {
            __builtin_amdgcn_s_waitcnt(0);
            __hip_atomic_fetch_add(&arr[(bid & 15) * 32], 1, __ATOMIC_RELAXED,
                                   __HIP_MEMORY_SCOPE_AGENT);
        }
        if (bid == 0) {
            if (tid < 16) {
                const int target = 4 * (t + 1);     // 64 blocks / 16 counters
                int guard = 0;
                while (__hip_atomic_load(&arr[tid * 32], __ATOMIC_RELAXED,
                                         __HIP_MEMORY_SCOPE_AGENT) < target
                       && guard < (1 << 20)) {
                    __builtin_amdgcn_s_sleep(1);
                    guard++;
                }
                __hip_atomic_store(&relcp[tid * 32], t + 1, __ATOMIC_RELAXED,
                                   __HIP_MEMORY_SCOPE_AGENT);
            }
        } else if (tid == 0) {
            int guard = 0;
            while (__hip_atomic_load(&relcp[(bid & 15) * 32], __ATOMIC_RELAXED,
                                     __HIP_MEMORY_SCOPE_AGENT) < t + 1
                   && guard < (1 << 20)) {
                __builtin_amdgcn_s_sleep(1);
                guard++;
            }
        }
        asm volatile("" ::: "memory");
        __syncthreads();
    }
}

// ---------------------------------------------------------------------------
__global__ void finish_k(const float* __restrict__ hsum, const float* __restrict__ hsel,
                         const float* __restrict__ t1sum, const float* __restrict__ t1sel,
                         const float* __restrict__ t2sum, const float* __restrict__ t2sel,
                         const int* __restrict__ targets, float* __restrict__ losssum)
{
    __shared__ float red[256];
    int n = blockIdx.x * 256 + threadIdx.x;
    float lp = 0.f;
    if (n < NR) {
        lp = hsel[n] - logf(hsum[n]);
        int tgt = targets[n];
        if (tgt >= CC1)      lp += t2sel[n] - logf(t2sum[n]);
        else if (tgt >= CC0) lp += t1sel[n] - logf(t1sum[n]);
    }
    red[threadIdx.x] = lp;
    __syncthreads();
    for (int s = 128; s > 0; s >>= 1) {
        if (threadIdx.x < s) red[threadIdx.x] += red[threadIdx.x + s];
        __syncthreads();
    }
    if (threadIdx.x == 0) atomicAdd(losssum, red[0]);
}

__global__ void out_k(const float* __restrict__ losssum, const float* __restrict__ hT,
                      float* __restrict__ out)
{
    int i = blockIdx.x * 256 + threadIdx.x;
    if (i == 0) out[0] = -losssum[0] / (float)NR;
    if (i < BBATCH * HD) out[1 + i] = hT[i];
}

// ---------------------------------------------------------------------------
extern "C" void kernel_launch(void* const* d_in, const int* in_sizes, int n_in,
                              void* d_out, int out_size, void* d_ws, size_t ws_size,
                              hipStream_t stream)
{
    const int*   x       = (const int*)d_in[0];
    const int*   lengths = (const int*)d_in[1];
    const float* hidden  = (const float*)d_in[2];
    const float* emb     = (const float*)d_in[3];
    const float* w_ih    = (const float*)d_in[4];
    const float* w_hh    = (const float*)d_in[5];
    const float* b_ih    = (const float*)d_in[6];
    const float* b_hh    = (const float*)d_in[7];
    const float* head_w  = (const float*)d_in[8];
    const float* p1      = (const float*)d_in[9];
    const float* t1      = (const float*)d_in[10];
    const float* p2      = (const float*)d_in[11];
    const float* t2      = (const float*)d_in[12];

    float* ws = (float*)d_ws;
    float* xp    = ws + OFF_XP;
    float* ys    = ws + OFF_YS;
    u16*   hb0   = (u16*)(ws + OFF_H0);   // 32768 bf16
    u16*   hb1   = hb0 + BBATCH * HD;     // 32768 bf16
    float* hT    = ws + OFF_H1;
    float* proj1 = ws + OFF_P1;
    float* proj2 = ws + OFF_P2;
    float* hsum  = ws + OFF_SUM;
    float* hsel  = hsum + 4064;
    float* t1sum = hsel + 4064;
    float* t1sel = t1sum + 4064;
    float* t2sum = t1sel + 4064;
    float* t2sel = t2sum + 4064;
    float* losss = ws + OFF_LOSS;
    int* ib      = (int*)(ws + OFF_INT);
    int* targets = ib;
    int* hselc   = ib + 4064;
    int* list1   = ib + 2 * 4064;
    int* list2   = ib + 3 * 4064;
    int* cnt1    = ib + 4 * 4064;
    int* cnt2    = cnt1 + 1;
    int* bar     = ib + 5 * 4064;    // 2048 ints: arr (16 lines) + relcp (16 lines)
    int* arr     = bar;
    int* relcp   = bar + 1024;

    float* out = (float*)d_out;

    init_k<<<232, 256, 0, stream>>>(hidden, hb0, hsum, cnt1, cnt2, bar);
    prep_k<<<16, 256, 0, stream>>>(x, targets, hselc, list1, list2, cnt1, cnt2);

    // xp = embed(x) @ w_ih^T + b_ih   [4064 x 3072]
    gemm_xp_k<<<dim3(32, 24), 256, 0, stream>>>(x, emb, w_ih, b_ih, xp);

    // GRU recurrence: one persistent MFMA kernel, internal per-step barrier
    gru_persist_k<<<NBG, 128, 0, stream>>>(xp, hidden, hb0, hb1, w_hh, b_hh,
                                           lengths, ys, hT, arr, relcp);

    // projections (all rows; cheap)
    gemm_ys_k<0><<<dim3(32, 2), 256, 0, stream>>>(ys, p1, HH1, proj1, HH1,
                                                  nullptr, nullptr, nullptr);
    gemm_ys_k<0><<<dim3(32, 1), 256, 0, stream>>>(ys, p2, HH2, proj2, HH2,
                                                  nullptr, nullptr, nullptr);
    // head logits + exp-sum + selected logit
    gemm_ys_k<1><<<dim3(32, 16), 256, 0, stream>>>(ys, head_w, CC0 + 2, nullptr, 0,
                                                   hsum, hsel, hselc);
    // tails over compacted cluster rows
    gemm_tail_k<<<dim3(32, 63), 256, 0, stream>>>(proj1, HH1, t1, SS1, list1, cnt1,
                                                  targets, CC0, t1sum, t1sel);
    gemm_tail_k<<<dim3(32, 313), 256, 0, stream>>>(proj2, HH2, t2, SS2, list2, cnt2,
                                                   targets, CC1, t2sum, t2sel);

    finish_k<<<16, 256, 0, stream>>>(hsum, hsel, t1sum, t1sel, t2sum, t2sel,
                                     targets, losss);
    out_k<<<128, 256, 0, stream>>>(losss, hT, out);
}

// Round 6
// 1533.723 us; speedup vs baseline: 3.4953x; 1.4267x over previous
//
#include <hip/hip_runtime.h>
#include <math.h>

// Problem constants
#define VV   50000
#define CC0  2000
#define CC1  10000
#define ED   512
#define HD   1024
#define BBATCH 32
#define TT   128
#define HH1  256
#define HH2  64
#define SS1  8000
#define SS2  40000
#define NR   4064        // B*(T-1) = 32*127
#define G3   3072        // 3*H

// Workspace layout (offsets in floats). Total ~70.2 MB (< 72.3 known-good).
#define OFF_XP   0ull                      // xp fp32: 12,484,608
#define OFF_YSB  12484608ull               // ys bf16: 4,161,536 u16 = 2,080,768 fl
#define OFF_HB   14565376ull               // hb0+hb1: 65,536 u16 = 32,768 fl
#define OFF_HT   14598144ull               // hT fp32: 32,768
#define OFF_P1B  14630912ull               // proj1 bf16: 1,040,384 u16 = 520,192 fl
#define OFF_P2B  15151104ull               // proj2 bf16: 260,096 u16 = 130,048 fl
#define OFF_WHB  15281152ull               // head_w bf16: 2,050,048 u16 = 1,025,024 fl
#define OFF_T1B  16306176ull               // t1 bf16: 2,048,000 u16 = 1,024,000 fl
#define OFF_PP1  17330176ull               // p1 bf16: 262,144 u16 = 131,072 fl
#define OFF_PP2  17461248ull               // p2 bf16: 65,536 u16 = 32,768 fl
#define OFF_SUM  17494016ull               // 6*4064 floats
#define OFF_LOSS (OFF_SUM + 6ull*4064ull)  // 64 floats
#define OFF_INT  (OFF_LOSS + 64ull)        // ints: targets,hselc,list1,list2,cnt,bar

#define ZERO_N (6*4064 + 64)
#define NBG 64            // GRU grid

typedef __attribute__((ext_vector_type(8))) __bf16 bf16x8;
typedef __attribute__((ext_vector_type(4))) float f32x4;
typedef __attribute__((ext_vector_type(4))) unsigned int u32x4;
typedef unsigned long long u64;
typedef unsigned short u16;
struct ull2s { u64 x, y; };

__device__ __forceinline__ u16 f2bf(float f) {
    unsigned u = __builtin_bit_cast(unsigned, f);
    u += 0x7fff + ((u >> 16) & 1);          // round-to-nearest-even
    return (u16)(u >> 16);
}

// ---------------------------------------------------------------------------
// init: h0 -> bf16 buffer, zero the sum/loss region, counters, barrier lines
__global__ void init_k(const float* __restrict__ hidden, u16* __restrict__ hb0,
                       float* __restrict__ zreg, int* __restrict__ cnt1,
                       int* __restrict__ cnt2, int* __restrict__ bar)
{
    int i = blockIdx.x * 256 + threadIdx.x;
    if (i < BBATCH * HD) hb0[i] = f2bf(hidden[i]);
    int zi = i - BBATCH * HD;
    if (zi >= 0 && zi < ZERO_N) zreg[zi] = 0.f;
    if (zi == ZERO_N) { *cnt1 = 0; *cnt2 = 0; }
    int bi = zi - (ZERO_N + 1);
    if (bi >= 0 && bi < 2048) bar[bi] = 0;
}

// prep: targets, head sel-cols, cluster row lists
__global__ void prep_k(const int* __restrict__ x, int* __restrict__ targets,
                       int* __restrict__ hselc, int* __restrict__ list1,
                       int* __restrict__ list2, int* __restrict__ cnt1, int* __restrict__ cnt2)
{
    int n = blockIdx.x * 256 + threadIdx.x;
    if (n >= NR) return;
    int b = n / 127, t = n % 127;
    int tgt = x[b * TT + t + 1];
    targets[n] = tgt;
    hselc[n] = (tgt < CC0) ? tgt : ((tgt < CC1) ? CC0 : CC0 + 1);
    if (tgt >= CC0 && tgt < CC1) list1[atomicAdd(cnt1, 1)] = n;
    else if (tgt >= CC1)         list2[atomicAdd(cnt2, 1)] = n;
}

// fp32 -> bf16 convert (n4 float4 groups)
__global__ void cvt_bf16_k(const float* __restrict__ src, u16* __restrict__ dst, int n4)
{
    int i = blockIdx.x * 256 + threadIdx.x;
    if (i >= n4) return;
    float4 f = *(const float4*)(src + 4 * (size_t)i);
    union { u16 h[4]; u64 v; } u;
    u.h[0] = f2bf(f.x); u.h[1] = f2bf(f.y); u.h[2] = f2bf(f.z); u.h[3] = f2bf(f.w);
    *(u64*)&dst[4 * (size_t)i] = u.v;
}

// ---------------------------------------------------------------------------
// GEMM: xp[r, c] = dot(emb[tok(r)], w_ih[c]) + b_ih[c]  (fp32, unchanged)
__global__ void __launch_bounds__(256)
gemm_xp_k(const int* __restrict__ x, const float* __restrict__ emb,
          const float* __restrict__ w_ih, const float* __restrict__ b_ih,
          float* __restrict__ xp)
{
    __shared__ float smem[2 * 16 * 132];
    __shared__ int tok[128];
    float* As = smem;
    float* Ws = smem + 16 * 132;
    const int tid = threadIdx.x;
    const int rbase = blockIdx.x * 128;
    const int cbase = blockIdx.y * 128;
    const int rg = tid >> 4, cg = tid & 15;
    const int rl = tid >> 1;
    const int kk0 = (tid & 1) * 8;

    if (tid < 128) {
        int r = rbase + tid;
        tok[tid] = (r < NR) ? x[(r & 31) * TT + (r >> 5)] : -1;
    }
    __syncthreads();

    float acc[8][8];
#pragma unroll
    for (int i = 0; i < 8; i++)
#pragma unroll
        for (int j = 0; j < 8; j++) acc[i][j] = 0.f;

    for (int k0 = 0; k0 < ED; k0 += 16) {
        int tk = tok[rl];
        float4 a0 = make_float4(0,0,0,0), a1 = a0;
        if (tk >= 0) {
            const float* ap = emb + (size_t)tk * ED + k0 + kk0;
            a0 = *(const float4*)(ap);
            a1 = *(const float4*)(ap + 4);
        }
        As[(kk0+0)*132 + rl] = a0.x; As[(kk0+1)*132 + rl] = a0.y;
        As[(kk0+2)*132 + rl] = a0.z; As[(kk0+3)*132 + rl] = a0.w;
        As[(kk0+4)*132 + rl] = a1.x; As[(kk0+5)*132 + rl] = a1.y;
        As[(kk0+6)*132 + rl] = a1.z; As[(kk0+7)*132 + rl] = a1.w;

        const float* wp = w_ih + (size_t)(cbase + rl) * ED + k0 + kk0;
        float4 w0 = *(const float4*)(wp);
        float4 w1 = *(const float4*)(wp + 4);
        Ws[(kk0+0)*132 + rl] = w0.x; Ws[(kk0+1)*132 + rl] = w0.y;
        Ws[(kk0+2)*132 + rl] = w0.z; Ws[(kk0+3)*132 + rl] = w0.w;
        Ws[(kk0+4)*132 + rl] = w1.x; Ws[(kk0+5)*132 + rl] = w1.y;
        Ws[(kk0+6)*132 + rl] = w1.z; Ws[(kk0+7)*132 + rl] = w1.w;
        __syncthreads();
#pragma unroll
        for (int kk = 0; kk < 16; kk++) {
            float4 va0 = *(float4*)&As[kk*132 + rg*8];
            float4 va1 = *(float4*)&As[kk*132 + rg*8 + 4];
            float4 vw0 = *(float4*)&Ws[kk*132 + cg*8];
            float4 vw1 = *(float4*)&Ws[kk*132 + cg*8 + 4];
            float av[8] = {va0.x,va0.y,va0.z,va0.w,va1.x,va1.y,va1.z,va1.w};
            float wv[8] = {vw0.x,vw0.y,vw0.z,vw0.w,vw1.x,vw1.y,vw1.z,vw1.w};
#pragma unroll
            for (int i = 0; i < 8; i++)
#pragma unroll
                for (int j = 0; j < 8; j++) acc[i][j] += av[i] * wv[j];
        }
        __syncthreads();
    }
#pragma unroll
    for (int i = 0; i < 8; i++) {
        int r = rbase + rg*8 + i;
        if (r >= NR) continue;
#pragma unroll
        for (int j = 0; j < 8; j++) {
            int c = cbase + cg*8 + j;
            xp[(size_t)r * G3 + c] = acc[i][j] + b_ih[c];
        }
    }
}

// ---------------------------------------------------------------------------
// bf16 MFMA GEMM, 128x128 tile, BK=32, 4 waves (2x2 of 64x64).
// A: bf16 rows (direct n or via rowmap/cnt). B: bf16 (or fp32 if BFP32) rows=cols.
// EPI 0: store C bf16 to outB. EPI 1: head exp-sum (selcol). EPI 2: tail exp-sum.
// MFMA layouts (HW-verified in GRU): A[m=lane&15][k=quad*8+j],
// B[n=lane&15][k=quad*8+j], C row=quad*4+reg, col=lane&15.
template<int EPI, int BFP32>
__global__ void __launch_bounds__(256)
mfma_gemm_k(const u16* __restrict__ Ab, const void* __restrict__ Bsrc,
            int Mdirect, int N, int K,
            const int* __restrict__ rowmap, const int* __restrict__ cntp,
            u16* __restrict__ outB, int ldo,
            float* __restrict__ gsum, float* __restrict__ gsel,
            const int* __restrict__ selcol, const int* __restrict__ targets, int lo)
{
    const int M = cntp ? *cntp : Mdirect;
    const int rbase = blockIdx.x * 128;
    if (rbase >= M) return;
    const int cbase = blockIdx.y * 128;

    __shared__ u16 As[128 * 40];
    __shared__ u16 Bs[128 * 40];
    __shared__ const u16* aptr[128];
    __shared__ int rown[128];
    __shared__ float redl[128 * 2];

    const int tid = threadIdx.x;
    if (tid < 128) {
        int rid = -1;
        if (rbase + tid < M) rid = rowmap ? rowmap[rbase + tid] : (rbase + tid);
        rown[tid] = rid;
        aptr[tid] = (rid >= 0) ? (Ab + (size_t)rid * K) : nullptr;
    }
    __syncthreads();

    const int lane = tid & 63, wid = tid >> 6;
    const int n16 = lane & 15, quad = lane >> 4;
    const int m0 = (wid >> 1) * 64, n0 = (wid & 1) * 64;
    const int i = tid >> 1, half = tid & 1;

    f32x4 acc[4][4];
#pragma unroll
    for (int a = 0; a < 4; a++)
#pragma unroll
        for (int b = 0; b < 4; b++) acc[a][b] = (f32x4){0.f, 0.f, 0.f, 0.f};

    for (int k0 = 0; k0 < K; k0 += 32) {
        // fetch A (bf16)
        const u16* ap = aptr[i];
        u32x4 a0 = {0,0,0,0}, a1 = a0;
        if (ap) {
            a0 = *(const u32x4*)(ap + k0 + half * 16);
            a1 = *(const u32x4*)(ap + k0 + half * 16 + 8);
        }
        // fetch B
        u32x4 b0 = {0,0,0,0}, b1 = b0;
        int c = cbase + i;
        if (c < N) {
            if (BFP32) {
                const float* bp = (const float*)Bsrc + (size_t)c * K + k0 + half * 16;
                float4 f0 = *(const float4*)(bp);
                float4 f1 = *(const float4*)(bp + 4);
                float4 f2 = *(const float4*)(bp + 8);
                float4 f3 = *(const float4*)(bp + 12);
                union { u16 h[16]; u32x4 v[2]; } u;
                u.h[0]=f2bf(f0.x); u.h[1]=f2bf(f0.y); u.h[2]=f2bf(f0.z); u.h[3]=f2bf(f0.w);
                u.h[4]=f2bf(f1.x); u.h[5]=f2bf(f1.y); u.h[6]=f2bf(f1.z); u.h[7]=f2bf(f1.w);
                u.h[8]=f2bf(f2.x); u.h[9]=f2bf(f2.y); u.h[10]=f2bf(f2.z); u.h[11]=f2bf(f2.w);
                u.h[12]=f2bf(f3.x); u.h[13]=f2bf(f3.y); u.h[14]=f2bf(f3.z); u.h[15]=f2bf(f3.w);
                b0 = u.v[0]; b1 = u.v[1];
            } else {
                const u16* bp = (const u16*)Bsrc + (size_t)c * K + k0 + half * 16;
                b0 = *(const u32x4*)(bp);
                b1 = *(const u32x4*)(bp + 8);
            }
        }
        __syncthreads();                    // previous compute done before overwrite
        *(u32x4*)&As[i * 40 + half * 16]     = a0;
        *(u32x4*)&As[i * 40 + half * 16 + 8] = a1;
        *(u32x4*)&Bs[i * 40 + half * 16]     = b0;
        *(u32x4*)&Bs[i * 40 + half * 16 + 8] = b1;
        __syncthreads();

        bf16x8 av[4], bv[4];
#pragma unroll
        for (int mi = 0; mi < 4; mi++)
            av[mi] = *(const bf16x8*)&As[(m0 + mi * 16 + n16) * 40 + quad * 8];
#pragma unroll
        for (int ni = 0; ni < 4; ni++)
            bv[ni] = *(const bf16x8*)&Bs[(n0 + ni * 16 + n16) * 40 + quad * 8];
#pragma unroll
        for (int mi = 0; mi < 4; mi++)
#pragma unroll
            for (int ni = 0; ni < 4; ni++)
                acc[mi][ni] = __builtin_amdgcn_mfma_f32_16x16x32_bf16(
                    av[mi], bv[ni], acc[mi][ni], 0, 0, 0);
    }

    __syncthreads();
    if (EPI == 0) {
#pragma unroll
        for (int mi = 0; mi < 4; mi++)
#pragma unroll
            for (int ni = 0; ni < 4; ni++)
#pragma unroll
                for (int r = 0; r < 4; r++) {
                    int row = rbase + m0 + mi * 16 + quad * 4 + r;
                    int col = cbase + n0 + ni * 16 + n16;
                    if (row < M && col < N)
                        outB[(size_t)row * ldo + col] = f2bf(acc[mi][ni][r]);
                }
    } else {
#pragma unroll
        for (int mi = 0; mi < 4; mi++)
#pragma unroll
            for (int r = 0; r < 4; r++) {
                int lrow = m0 + mi * 16 + quad * 4 + r;
                int nid = rown[lrow];
                float s = 0.f;
                if (nid >= 0) {
                    int sc = (EPI == 1) ? selcol[nid] : (targets[nid] - lo);
#pragma unroll
                    for (int ni = 0; ni < 4; ni++) {
                        int col = cbase + n0 + ni * 16 + n16;
                        if (col < N) {
                            float v = acc[mi][ni][r];
                            s += __expf(v);
                            if (col == sc) gsel[nid] = v;
                        }
                    }
                }
                s += __shfl_xor(s, 1);
                s += __shfl_xor(s, 2);
                s += __shfl_xor(s, 4);
                s += __shfl_xor(s, 8);
                if (n16 == 0) redl[lrow * 2 + (wid & 1)] = s;
            }
        __syncthreads();
        if (tid < 128) {
            int nid = rown[tid];
            if (nid >= 0) atomicAdd(&gsum[nid], redl[tid * 2] + redl[tid * 2 + 1]);
        }
    }
}

// ---------------------------------------------------------------------------
// Persistent MFMA GRU: 64 blocks x 128 threads. Distributed grid barrier:
// each block relaxed-stores t+1 to its own line; wave 0 polls all 64 flags
// (one lane per flag). h bf16 via LLC-coherent relaxed agent atomics.
// ys written bf16, n-ordered (row = b*127 + t).
__global__ void __launch_bounds__(128, 1)
gru_persist_k(const float* __restrict__ xp, const float* __restrict__ hidden,
              u16* __restrict__ hb0, u16* __restrict__ hb1,
              const float* __restrict__ w_hh, const float* __restrict__ b_hh,
              const int* __restrict__ lengths, u16* __restrict__ ys,
              float* __restrict__ hT, int* __restrict__ arr)
{
    __shared__ u16 Blds[48 * 1032];          // 97 KB, row = g*16+c, +8 pad
    const int tid = threadIdx.x;
    const int bid = blockIdx.x;
    const int j0 = bid * 16;
    const int lane = tid & 63, wid = tid >> 6;
    const int n16 = lane & 15, quad = lane >> 4;

    for (int idx = tid; idx < 48 * 1024; idx += 128) {
        int r = idx >> 10, k = idx & 1023;
        int g = r >> 4, c = r & 15;
        Blds[r * 1032 + k] = f2bf(w_hh[(size_t)(g * HD + j0 + c) * HD + k]);
    }

    const int col = j0 + n16;
    float bh0 = b_hh[col], bh1 = b_hh[HD + col], bh2 = b_hh[2 * HD + col];
    float hold[4];
    int len[4];
#pragma unroll
    for (int r = 0; r < 4; r++) {
        int b = wid * 16 + quad * 4 + r;
        len[r] = lengths[b];
        hold[r] = hidden[b * HD + col];
    }
    __syncthreads();

    for (int t = 0; t < TT - 1; t++) {
        const u16* hb = (t & 1) ? hb1 : hb0;
        u16* hbn = (t & 1) ? hb0 : hb1;

        float xrv[4], xzv[4], xnv[4];
#pragma unroll
        for (int r = 0; r < 4; r++) {
            int b = wid * 16 + quad * 4 + r;
            const float* xpt = xp + ((size_t)t * BBATCH + b) * G3 + col;
            xrv[r] = xpt[0]; xzv[r] = xpt[HD]; xnv[r] = xpt[2 * HD];
        }

        const u16* arow = hb + (size_t)(wid * 16 + n16) * HD + quad * 8;
        u64 apf[64];
#pragma unroll
        for (int ks = 0; ks < 32; ks++) {
            apf[2*ks]   = __hip_atomic_load((const u64*)(arow + ks*32),
                                            __ATOMIC_RELAXED, __HIP_MEMORY_SCOPE_AGENT);
            apf[2*ks+1] = __hip_atomic_load((const u64*)(arow + ks*32 + 4),
                                            __ATOMIC_RELAXED, __HIP_MEMORY_SCOPE_AGENT);
        }

        f32x4 acc0 = {0.f, 0.f, 0.f, 0.f}, acc1 = acc0, acc2 = acc0;
        const int boff = n16 * 1032 + quad * 8;
#pragma unroll
        for (int ks = 0; ks < 32; ks++) {
            ull2s av2; av2.x = apf[2*ks]; av2.y = apf[2*ks+1];
            bf16x8 av = __builtin_bit_cast(bf16x8, av2);
            bf16x8 b0 = *(const bf16x8*)&Blds[boff + ks*32];
            bf16x8 b1 = *(const bf16x8*)&Blds[16*1032 + boff + ks*32];
            bf16x8 b2 = *(const bf16x8*)&Blds[32*1032 + boff + ks*32];
            acc0 = __builtin_amdgcn_mfma_f32_16x16x32_bf16(av, b0, acc0, 0, 0, 0);
            acc1 = __builtin_amdgcn_mfma_f32_16x16x32_bf16(av, b1, acc1, 0, 0, 0);
            acc2 = __builtin_amdgcn_mfma_f32_16x16x32_bf16(av, b2, acc2, 0, 0, 0);
        }

#pragma unroll
        for (int r = 0; r < 4; r++) {
            int b = wid * 16 + quad * 4 + r;
            float hr = acc0[r] + bh0, hz = acc1[r] + bh1, hn = acc2[r] + bh2;
            float rg = 1.f / (1.f + __expf(-(xrv[r] + hr)));
            float zg = 1.f / (1.f + __expf(-(xzv[r] + hz)));
            float nv = tanhf(xnv[r] + rg * hn);
            bool valid = t < (len[r] - 1);
            float hnew = valid ? (1.f - zg) * nv + zg * hold[r] : hold[r];
            hold[r] = hnew;
            __hip_atomic_store(hbn + (size_t)b * HD + col, f2bf(hnew),
                               __ATOMIC_RELAXED, __HIP_MEMORY_SCOPE_AGENT);
            ys[((size_t)b * 127 + t) * HD + col] = f2bf(valid ? hnew : 0.f);
            if (t == TT - 2) hT[b * HD + col] = hnew;
        }

        // ---- distributed grid barrier: own-flag store + all-flag poll ----
        __syncthreads();                  // drains each wave's vmem (h stores acked)
        if (tid < 64) {
            if (tid == 0) {
                __builtin_amdgcn_s_waitcnt(0);
                __hip_atomic_store(&arr[bid * 32], t + 1, __ATOMIC_RELAXED,
                                   __HIP_MEMORY_SCOPE_AGENT);
            }
            int guard = 0;
            while (__hip_atomic_load(&arr[tid * 32], __ATOMIC_RELAXED,
                                     __HIP_MEMORY_SCOPE_AGENT) < t + 1
                   && guard < (1 << 20)) {
                __builtin_amdgcn_s_sleep(1);
                guard++;
            }
        }
        asm volatile("" ::: "memory");
        __syncthreads();
    }
}

// ---------------------------------------------------------------------------
__global__ void finish_k(const float* __restrict__ hsum, const float* __restrict__ hsel,
                         const float* __restrict__ t1sum, const float* __restrict__ t1sel,
                         const float* __restrict__ t2sum, const float* __restrict__ t2sel,
                         const int* __restrict__ targets, float* __restrict__ losssum)
{
    __shared__ float red[256];
    int n = blockIdx.x * 256 + threadIdx.x;
    float lp = 0.f;
    if (n < NR) {
        lp = hsel[n] - logf(hsum[n]);
        int tgt = targets[n];
        if (tgt >= CC1)      lp += t2sel[n] - logf(t2sum[n]);
        else if (tgt >= CC0) lp += t1sel[n] - logf(t1sum[n]);
    }
    red[threadIdx.x] = lp;
    __syncthreads();
    for (int s = 128; s > 0; s >>= 1) {
        if (threadIdx.x < s) red[threadIdx.x] += red[threadIdx.x + s];
        __syncthreads();
    }
    if (threadIdx.x == 0) atomicAdd(losssum, red[0]);
}

__global__ void out_k(const float* __restrict__ losssum, const float* __restrict__ hT,
                      float* __restrict__ out)
{
    int i = blockIdx.x * 256 + threadIdx.x;
    if (i == 0) out[0] = -losssum[0] / (float)NR;
    if (i < BBATCH * HD) out[1 + i] = hT[i];
}

// ---------------------------------------------------------------------------
extern "C" void kernel_launch(void* const* d_in, const int* in_sizes, int n_in,
                              void* d_out, int out_size, void* d_ws, size_t ws_size,
                              hipStream_t stream)
{
    const int*   x       = (const int*)d_in[0];
    const int*   lengths = (const int*)d_in[1];
    const float* hidden  = (const float*)d_in[2];
    const float* emb     = (const float*)d_in[3];
    const float* w_ih    = (const float*)d_in[4];
    const float* w_hh    = (const float*)d_in[5];
    const float* b_ih    = (const float*)d_in[6];
    const float* b_hh    = (const float*)d_in[7];
    const float* head_w  = (const float*)d_in[8];
    const float* p1      = (const float*)d_in[9];
    const float* t1      = (const float*)d_in[10];
    const float* p2      = (const float*)d_in[11];
    const float* t2      = (const float*)d_in[12];

    float* ws = (float*)d_ws;
    float* xp    = ws + OFF_XP;
    u16*   ysb   = (u16*)(ws + OFF_YSB);
    u16*   hb0   = (u16*)(ws + OFF_HB);
    u16*   hb1   = hb0 + BBATCH * HD;
    float* hT    = ws + OFF_HT;
    u16*   p1b   = (u16*)(ws + OFF_P1B);   // proj1 bf16 out
    u16*   p2b   = (u16*)(ws + OFF_P2B);   // proj2 bf16 out
    u16*   whb   = (u16*)(ws + OFF_WHB);   // head_w bf16
    u16*   t1b   = (u16*)(ws + OFF_T1B);   // t1 bf16
    u16*   pp1b  = (u16*)(ws + OFF_PP1);   // p1 bf16
    u16*   pp2b  = (u16*)(ws + OFF_PP2);   // p2 bf16
    float* hsum  = ws + OFF_SUM;
    float* hsel  = hsum + 4064;
    float* t1sum = hsel + 4064;
    float* t1sel = t1sum + 4064;
    float* t2sum = t1sel + 4064;
    float* t2sel = t2sum + 4064;
    float* losss = ws + OFF_LOSS;
    int* ib      = (int*)(ws + OFF_INT);
    int* targets = ib;
    int* hselc   = ib + 4064;
    int* list1   = ib + 2 * 4064;
    int* list2   = ib + 3 * 4064;
    int* cnt1    = ib + 4 * 4064;
    int* cnt2    = cnt1 + 1;
    int* bar     = ib + 5 * 4064;    // 2048 ints: 64 flags x 32-int stride

    float* out = (float*)d_out;

    init_k<<<232, 256, 0, stream>>>(hidden, hb0, hsum, cnt1, cnt2, bar);
    prep_k<<<16, 256, 0, stream>>>(x, targets, hselc, list1, list2, cnt1, cnt2);

    // weight converts fp32 -> bf16 (t2 converted on-the-fly in its GEMM)
    cvt_bf16_k<<<(512512 + 255) / 256, 256, 0, stream>>>(head_w, whb, 512512);
    cvt_bf16_k<<<(512000 + 255) / 256, 256, 0, stream>>>(t1, t1b, 512000);
    cvt_bf16_k<<<(65536 + 255) / 256, 256, 0, stream>>>(p1, pp1b, 65536);
    cvt_bf16_k<<<(16384 + 255) / 256, 256, 0, stream>>>(p2, pp2b, 16384);

    // xp = embed(x) @ w_ih^T + b_ih   [4064 x 3072] fp32
    gemm_xp_k<<<dim3(32, 24), 256, 0, stream>>>(x, emb, w_ih, b_ih, xp);

    // GRU recurrence: persistent MFMA kernel, distributed barrier
    gru_persist_k<<<NBG, 128, 0, stream>>>(xp, hidden, hb0, hb1, w_hh, b_hh,
                                           lengths, ysb, hT, bar);

    // proj1 = ys @ p1^T  -> bf16 [4064 x 256]
    mfma_gemm_k<0, 0><<<dim3(32, 2), 256, 0, stream>>>(
        ysb, pp1b, NR, HH1, HD, nullptr, nullptr, p1b, HH1,
        nullptr, nullptr, nullptr, nullptr, 0);
    // proj2 = ys @ p2^T  -> bf16 [4064 x 64]
    mfma_gemm_k<0, 0><<<dim3(32, 1), 256, 0, stream>>>(
        ysb, pp2b, NR, HH2, HD, nullptr, nullptr, p2b, HH2,
        nullptr, nullptr, nullptr, nullptr, 0);
    // head: exp-sum + selected logit
    mfma_gemm_k<1, 0><<<dim3(32, 16), 256, 0, stream>>>(
        ysb, whb, NR, CC0 + 2, HD, nullptr, nullptr, nullptr, 0,
        hsum, hsel, hselc, nullptr, 0);
    // tail1 over compacted rows
    mfma_gemm_k<2, 0><<<dim3(32, 63), 256, 0, stream>>>(
        p1b, t1b, 0, SS1, HH1, list1, cnt1, nullptr, 0,
        t1sum, t1sel, nullptr, targets, CC0);
    // tail2 over compacted rows, B = fp32 t2 converted on the fly
    mfma_gemm_k<2, 1><<<dim3(32, 313), 256, 0, stream>>>(
        p2b, t2, 0, SS2, HH2, list2, cnt2, nullptr, 0,
        t2sum, t2sel, nullptr, targets, CC1);

    finish_k<<<16, 256, 0, stream>>>(hsum, hsel, t1sum, t1sel, t2sum, t2sel,
                                     targets, losss);
    out_k<<<128, 256, 0, stream>>>(losss, hT, out);
}